// Round 1
// baseline (1201.781 us; speedup 1.0000x reference)
//
#include <hip/hip_runtime.h>
#include <hip/hip_bf16.h>
#include <math.h>

#define NN 100000
#define NE 1600000
#define FF 64
#define NB 64
#define NSCAN_BLOCKS 391   // ceil(NN/256)

// avg_deg['log'] = sum(log(i+1)*DEG[i]) / sum(DEG)
__device__ __constant__ float AVG_LOG_F = 1.9595436f;

typedef short short8 __attribute__((ext_vector_type(8)));
typedef float f32x4 __attribute__((ext_vector_type(4)));

__device__ __forceinline__ void atomAddF(float* p, float v) {
    __hip_atomic_fetch_add(p, v, __ATOMIC_RELAXED, __HIP_MEMORY_SCOPE_AGENT);
}
__device__ __forceinline__ float bf2f(short v) {
    return __uint_as_float(((unsigned)(unsigned short)v) << 16);
}
__device__ __forceinline__ unsigned packbf2(float a, float b) {
    unsigned ua = (unsigned)(unsigned short)__bfloat16_as_short(__float2bfloat16(a));
    unsigned ub = (unsigned)(unsigned short)__bfloat16_as_short(__float2bfloat16(b));
    return ua | (ub << 16);
}
// D = a.lo*b.lo + a.hi*b.hi + c  (bf16 pairs, f32 accumulate)
__device__ __forceinline__ float dot2bf(unsigned a, unsigned b, float c) {
    float d;
    asm("v_dot2_f32_bf16 %0, %1, %2, %3" : "=v"(d) : "v"(a), "v"(b), "v"(c));
    return d;
}

// ---------------- fold weights: Wtb = (Wo@Wl)^T bf16; Wepp = packed-bf16 (We@Wp2); biases ----------------
__global__ void fold_weights(const float* __restrict__ Wo, const float* __restrict__ Wl,
                             const float* __restrict__ bo, const float* __restrict__ bl,
                             const float* __restrict__ We, const float* __restrict__ Wp,
                             const float* __restrict__ bp, const float* __restrict__ be,
                             __hip_bfloat16* __restrict__ Wtb,   // [64][832]  Wtb[f][k] = (Wo@Wl)[k][f]
                             unsigned* __restrict__ Wepp,        // [8][64] packed bf16 pairs of Wep[k][f]
                             float* __restrict__ bpF, float* __restrict__ boF) {
    int t = blockIdx.x * blockDim.x + threadIdx.x;
    if (t < 832 * 64) {
        int k = t >> 6, f = t & 63;
        float acc = 0.f;
        for (int j = 0; j < 64; j++) acc += Wo[k * 64 + j] * Wl[j * 64 + f];
        Wtb[f * 832 + k] = __float2bfloat16(acc);
    } else if (t < 832 * 64 + 512) {
        int u = t - 832 * 64; int k2 = u >> 6, f = u & 63;
        float a0 = 0.f, a1 = 0.f;
        for (int j = 0; j < 64; j++) {
            float wp = Wp[(128 + j) * 64 + f];
            a0 += We[(2 * k2) * 64 + j] * wp;
            a1 += We[(2 * k2 + 1) * 64 + j] * wp;
        }
        Wepp[k2 * 64 + f] = packbf2(a0, a1);
    } else if (t < 832 * 64 + 512 + 64) {
        int f = t - (832 * 64 + 512);
        float acc = bl[f];
        for (int j = 0; j < 64; j++) acc += bo[j] * Wl[j * 64 + f];
        boF[f] = acc;
    } else if (t < 832 * 64 + 512 + 128) {
        int f = t - (832 * 64 + 512 + 64);
        float acc = bp[f];
        for (int j = 0; j < 64; j++) acc += be[j] * Wp[(128 + j) * 64 + f];
        bpF[f] = acc;
    }
}

// ---------------- node pre-MLP + A/B projections (wave per node); Bn stored bf16 ----------------
__global__ __launch_bounds__(256) void node_pre(const float* __restrict__ x,
                                                const float* __restrict__ W1, const float* __restrict__ b1,
                                                const float* __restrict__ W2, const float* __restrict__ b2,
                                                const float* __restrict__ Wp,
                                                float* __restrict__ x2, float* __restrict__ A,
                                                __hip_bfloat16* __restrict__ Bnb) {
    __shared__ float W1s[64 * 32], W2s[32 * 64], Wp0s[64 * 64], Wp1s[64 * 64];
    __shared__ float xs[4][64], ts[4][32], x2s[4][64];
    int tid = threadIdx.x;
    for (int i = tid; i < 2048; i += 256) W1s[i] = W1[i];
    for (int i = tid; i < 2048; i += 256) W2s[i] = W2[i];
    for (int i = tid; i < 4096; i += 256) Wp0s[i] = Wp[i];
    for (int i = tid; i < 4096; i += 256) Wp1s[i] = Wp[4096 + i];
    __syncthreads();
    int w = tid >> 6, f = tid & 63;
    int wid = blockIdx.x * 4 + w;
    int nw = gridDim.x * 4;
    for (int v = wid; v < NN; v += nw) {
        xs[w][f] = x[(size_t)v * 64 + f];
        if (f < 32) {
            float tj = b1[f];
            for (int k = 0; k < 64; k++) tj += xs[w][k] * W1s[k * 32 + f];
            ts[w][f] = fmaxf(tj, 0.f);
        }
        float acc2 = b2[f];
        for (int k = 0; k < 32; k++) acc2 += ts[w][k] * W2s[k * 64 + f];
        x2s[w][f] = acc2;
        x2[(size_t)v * 64 + f] = acc2;
        float aa = 0.f, bb = 0.f;
        for (int k = 0; k < 64; k++) {
            float xv = x2s[w][k];
            aa += xv * Wp0s[k * 64 + f];
            bb += xv * Wp1s[k * 64 + f];
        }
        A[(size_t)v * 64 + f] = aa;
        Bnb[(size_t)v * 64 + f] = __float2bfloat16(bb);
    }
}

// ---------------- counting sort of edges by dst ----------------
__global__ void hist_kernel(const int* __restrict__ ei, unsigned* __restrict__ cnt_i) {
    int t = blockIdx.x * blockDim.x + threadIdx.x;
    if (t < NE) atomicAdd(&cnt_i[ei[NE + t]], 1u);
}

__global__ void scan_blocksum(const unsigned* __restrict__ cnt_i, unsigned* __restrict__ bsum) {
    __shared__ unsigned red[256];
    int t = blockIdx.x * 256 + threadIdx.x;
    unsigned c = (t < NN) ? cnt_i[t] : 0u;
    red[threadIdx.x] = c; __syncthreads();
    for (int s = 128; s > 0; s >>= 1) {
        if (threadIdx.x < s) red[threadIdx.x] += red[threadIdx.x + s];
        __syncthreads();
    }
    if (threadIdx.x == 0) bsum[blockIdx.x] = red[0];
}

__global__ void scan_top(const unsigned* __restrict__ bsum, unsigned* __restrict__ boff,
                         unsigned* __restrict__ start) {
    __shared__ unsigned sh[512];
    int t = threadIdx.x;
    unsigned v = (t < NSCAN_BLOCKS) ? bsum[t] : 0u;
    sh[t] = v; __syncthreads();
    for (int d = 1; d < 512; d <<= 1) {
        unsigned add = (t >= d) ? sh[t - d] : 0u;
        __syncthreads();
        sh[t] += add;
        __syncthreads();
    }
    if (t < NSCAN_BLOCKS) boff[t] = sh[t] - v;   // exclusive
    if (t == 0) start[NN] = NE;
}

__global__ void scan_final(const unsigned* __restrict__ cnt_i, const unsigned* __restrict__ boff,
                           unsigned* __restrict__ start) {
    __shared__ unsigned sh[256];
    int b = blockIdx.x, t = threadIdx.x;
    int v = b * 256 + t;
    unsigned c = (v < NN) ? cnt_i[v] : 0u;
    sh[t] = c; __syncthreads();
    for (int d = 1; d < 256; d <<= 1) {
        unsigned add = (t >= d) ? sh[t - d] : 0u;
        __syncthreads();
        sh[t] += add;
        __syncthreads();
    }
    if (v < NN) start[v] = boff[b] + sh[t] - c;  // exclusive scan
}

// ---------------- degree-sorted node permutation (counting sort by in-degree) ----------------
__global__ void deg_hist(const unsigned* __restrict__ start, unsigned* __restrict__ dh) {
    int t = blockIdx.x * blockDim.x + threadIdx.x;
    if (t < NN) {
        unsigned d = start[t + 1] - start[t];
        if (d > 255u) d = 255u;
        atomicAdd(&dh[d], 1u);
    }
}
__global__ void deg_scan(const unsigned* __restrict__ dh, unsigned* __restrict__ doff) {
    __shared__ unsigned sh[256];
    int t = threadIdx.x;
    unsigned v = dh[t];
    sh[t] = v; __syncthreads();
    for (int d = 1; d < 256; d <<= 1) {
        unsigned add = (t >= d) ? sh[t - d] : 0u;
        __syncthreads();
        sh[t] += add;
        __syncthreads();
    }
    doff[t] = sh[t] - v;   // exclusive
}
__global__ void deg_scatter(const unsigned* __restrict__ start, unsigned* __restrict__ doff,
                            int* __restrict__ perm) {
    int t = blockIdx.x * blockDim.x + threadIdx.x;
    if (t < NN) {
        unsigned d = start[t + 1] - start[t];
        if (d > 255u) d = 255u;
        unsigned pos = atomicAdd(&doff[d], 1u);
        perm[pos] = t;
    }
}

// scatter: materialize sorted edge payloads (src and bf16 edge_attr); pads element NE
__global__ void scatter_kernel(const int* __restrict__ ei, const float* __restrict__ ea,
                               const unsigned* __restrict__ start,
                               unsigned* __restrict__ cnt_i,
                               __hip_bfloat16* __restrict__ eab, int* __restrict__ src_s) {
    int t = blockIdx.x * blockDim.x + threadIdx.x;
    if (t == 0) {
        src_s[NE] = 0;
        short8 z = {0, 0, 0, 0, 0, 0, 0, 0};
        short8* p = (short8*)(eab + (size_t)NE * 16);
        p[0] = z; p[1] = z;
    }
    if (t < NE) {
        int d = ei[NE + t];
        unsigned old = atomicSub(&cnt_i[d], 1u);
        unsigned pos = start[d] + old - 1u;
        src_s[pos] = ei[t];
        const float4* s4 = (const float4*)(ea + (size_t)t * 16);
        float4 a = s4[0], b = s4[1], c = s4[2], e = s4[3];
        short8 o0, o1;
        o0[0] = (short)__bfloat16_as_short(__float2bfloat16(a.x));
        o0[1] = (short)__bfloat16_as_short(__float2bfloat16(a.y));
        o0[2] = (short)__bfloat16_as_short(__float2bfloat16(a.z));
        o0[3] = (short)__bfloat16_as_short(__float2bfloat16(a.w));
        o0[4] = (short)__bfloat16_as_short(__float2bfloat16(b.x));
        o0[5] = (short)__bfloat16_as_short(__float2bfloat16(b.y));
        o0[6] = (short)__bfloat16_as_short(__float2bfloat16(b.z));
        o0[7] = (short)__bfloat16_as_short(__float2bfloat16(b.w));
        o1[0] = (short)__bfloat16_as_short(__float2bfloat16(c.x));
        o1[1] = (short)__bfloat16_as_short(__float2bfloat16(c.y));
        o1[2] = (short)__bfloat16_as_short(__float2bfloat16(c.z));
        o1[3] = (short)__bfloat16_as_short(__float2bfloat16(c.w));
        o1[4] = (short)__bfloat16_as_short(__float2bfloat16(e.x));
        o1[5] = (short)__bfloat16_as_short(__float2bfloat16(e.y));
        o1[6] = (short)__bfloat16_as_short(__float2bfloat16(e.z));
        o1[7] = (short)__bfloat16_as_short(__float2bfloat16(e.w));
        short8* dst8 = (short8*)(eab + (size_t)pos * 16);
        dst8[0] = o0; dst8[1] = o1;
    }
}

// ---------------- fused aggregation + post GEMM (MFMA) + BN stats ----------------
// block = 256 = 4 waves = 16 nodes, chosen via degree-sorted perm so the 16 nodes
// have near-equal degree (kills maxlen padding). All segment indices/pointers are
// wave-uniform via readfirstlane -> scalar/saddr loads, zero per-lane address math.
// e-dot uses v_dot2_f32_bf16 against pre-packed bf16 Wep pairs (no bf16 decode).
__global__ __launch_bounds__(256) void agg_post_kernel(const __hip_bfloat16* __restrict__ eab,
                                                       const int* __restrict__ src_s,
                                                       const unsigned* __restrict__ start,
                                                       const int* __restrict__ perm,
                                                       const float* __restrict__ A,
                                                       const unsigned short* __restrict__ Bnb,
                                                       const float* __restrict__ x2,
                                                       const unsigned* __restrict__ Wepp, const float* __restrict__ bpF,
                                                       const __hip_bfloat16* __restrict__ Wtb,
                                                       const float* __restrict__ boF,
                                                       float* __restrict__ out_pre,
                                                       float* __restrict__ bnsum, float* __restrict__ bnsum2) {
    __shared__ __hip_bfloat16 As[16 * 840];
    __shared__ int pvs[16];
    int tid = threadIdx.x;
    int w = __builtin_amdgcn_readfirstlane(tid >> 6);   // wave id, force SGPR
    int f = tid & 63;
    int base = blockIdx.x * 16;      // 6250 blocks exactly

    unsigned wcolp[8];
    #pragma unroll
    for (int k = 0; k < 8; k++) wcolp[k] = Wepp[k * 64 + f];
    float bpf = bpF[f];

    int vv[4]; unsigned s0[4]; int len[4], lim[4]; float av[4];
    float sA[4] = {0.f, 0.f, 0.f, 0.f}, s2A[4] = {0.f, 0.f, 0.f, 0.f};
    float mnA[4], mxA[4];
    int maxlen = 0;
    #pragma unroll
    for (int g = 0; g < 4; ++g) {
        int v = __builtin_amdgcn_readfirstlane(perm[base + g * 4 + w]);
        vv[g] = v;
        if (f == 0) pvs[g * 4 + w] = v;
        unsigned a = start[v], b = start[v + 1];
        s0[g] = a; len[g] = (int)(b - a);
        lim[g] = len[g] > 0 ? len[g] - 1 : 0;
        maxlen = max(maxlen, len[g]);
        av[g] = A[(size_t)v * 64 + f] + bpf;
        mnA[g] = INFINITY; mxA[g] = -INFINITY;
    }

    for (int j = 0; j < maxlen; ++j) {
        #pragma unroll
        for (int g = 0; g < 4; ++g) {
            unsigned idx = s0[g] + (unsigned)min(j, lim[g]);   // wave-uniform
            const unsigned* e32 = (const unsigned*)(eab + (size_t)idx * 16);
            int src = src_s[idx];                               // wave-uniform
            const unsigned short* brow = Bnb + ((size_t)src << 6);
            float h = av[g];
            #pragma unroll
            for (int k = 0; k < 8; k++) h = dot2bf(e32[k], wcolp[k], h);
            h += bf2f((short)brow[f]);                          // SGPR base + f*2 voffset
            bool valid = j < len[g];
            float hm = valid ? h : 0.f;
            sA[g] += hm; s2A[g] += hm * hm;
            // clamped duplicates are idempotent for min/max; deg-0 fixed by `has` below
            mnA[g] = fminf(mnA[g], h);
            mxA[g] = fmaxf(mxA[g], h);
        }
    }

    #pragma unroll
    for (int g = 0; g < 4; ++g) {
        int n = g * 4 + w;
        int v = vv[g];
        float c = (float)len[g];
        float d = fmaxf(c, 1.f);
        float inv = 1.f / d;
        float mean = sA[g] * inv, mean2 = s2A[g] * inv;
        float sd = sqrtf(fmaxf(mean2 - mean * mean, 0.f) + 1e-5f);
        bool has = len[g] > 0;
        float mn = has ? mnA[g] : 0.f;
        float mx = has ? mxA[g] : 0.f;
        float l = __logf(d + 1.f);
        float amp = l * (1.0f / 1.9595436f);
        float iamp = 1.9595436f / l;
        __hip_bfloat16* row = &As[n * 840];
        row[f]        = __float2bfloat16(x2[(size_t)v * 64 + f]);
        row[64 + f]   = __float2bfloat16(mean);
        row[128 + f]  = __float2bfloat16(mn);
        row[192 + f]  = __float2bfloat16(mx);
        row[256 + f]  = __float2bfloat16(sd);
        row[320 + f]  = __float2bfloat16(mean * amp);
        row[384 + f]  = __float2bfloat16(mn * amp);
        row[448 + f]  = __float2bfloat16(mx * amp);
        row[512 + f]  = __float2bfloat16(sd * amp);
        row[576 + f]  = __float2bfloat16(mean * iamp);
        row[640 + f]  = __float2bfloat16(mn * iamp);
        row[704 + f]  = __float2bfloat16(mx * iamp);
        row[768 + f]  = __float2bfloat16(sd * iamp);
    }
    __syncthreads();

    // MFMA phase: lane = m + 16q; A[m][k=q*8+j], B[k][n=m]; D: col=lane&15, row=q*4+reg
    int m = f & 15, q = f >> 4;
    int fbase = w * 16;
    f32x4 acc = {0.f, 0.f, 0.f, 0.f};
    const __hip_bfloat16* arow = &As[m * 840 + q * 8];
    const __hip_bfloat16* brow = &Wtb[(size_t)(fbase + m) * 832 + q * 8];
    #pragma unroll
    for (int s = 0; s < 26; ++s) {
        short8 af = *(const short8*)(arow + s * 32);
        short8 bf = *(const short8*)(brow + s * 32);
        acc = __builtin_amdgcn_mfma_f32_16x16x32_bf16(af, bf, acc, 0, 0, 0);
    }

    float bof = boF[fbase + m];
    float p1 = 0.f, p2 = 0.f;
    #pragma unroll
    for (int r = 0; r < 4; ++r) {
        float vvv = acc[r] + bof;
        int vn = pvs[q * 4 + r];
        out_pre[(size_t)vn * 64 + fbase + m] = vvv;
        p1 += vvv; p2 += vvv * vvv;
    }
    p1 += __shfl_xor(p1, 16); p2 += __shfl_xor(p2, 16);
    p1 += __shfl_xor(p1, 32); p2 += __shfl_xor(p2, 32);
    if (f < 16) {
        atomAddF(&bnsum[fbase + f], p1);
        atomAddF(&bnsum2[fbase + f], p2);
    }
}

// ---------------- BN finalize ----------------
__global__ void bn_finalize(const float* __restrict__ bnsum, const float* __restrict__ bnsum2,
                            const float* __restrict__ gamma, const float* __restrict__ beta,
                            float* __restrict__ bnscale, float* __restrict__ bnshift) {
    int f = threadIdx.x;
    if (f < 64) {
        float mu = bnsum[f] * (1.0f / NN);
        float var = bnsum2[f] * (1.0f / NN) - mu * mu;
        float sc = gamma[f] / sqrtf(var + 1e-5f);
        bnscale[f] = sc;
        bnshift[f] = beta[f] - mu * sc;
    }
}

// ---------------- BN apply + ReLU + global_add_pool ----------------
__global__ __launch_bounds__(256) void bn_pool(const float* __restrict__ out_pre, const int* __restrict__ batch,
                                               const float* __restrict__ bnscale, const float* __restrict__ bnshift,
                                               float* __restrict__ pooled) {
    __shared__ float red[256];
    int tid = threadIdx.x, f = tid & 63, q = tid >> 6;
    int base = blockIdx.x * 64;
    float sc = bnscale[f], sh = bnshift[f];
    int b_first = batch[base < NN ? base : NN - 1];
    int last = base + 63; if (last >= NN) last = NN - 1;
    int b_last = batch[last];
    if (b_first == b_last) {
        float local = 0.f;
        for (int g = 0; g < 16; ++g) {
            int v = base + g * 4 + q;
            if (v < NN) local += fmaxf(out_pre[(size_t)v * 64 + f] * sc + sh, 0.f);
        }
        red[tid] = local;
        __syncthreads();
        if (tid < 64) atomAddF(&pooled[b_first * 64 + f], red[f] + red[f + 64] + red[f + 128] + red[f + 192]);
    } else {
        for (int g = 0; g < 16; ++g) {
            int v = base + g * 4 + q;
            if (v < NN) {
                float val = fmaxf(out_pre[(size_t)v * 64 + f] * sc + sh, 0.f);
                atomAddF(&pooled[batch[v] * 64 + f], val);
            }
        }
    }
}

// ---------------- head MLP: relu(pooled@Wm1+bm1)@Wm2+bm2 ----------------
__global__ void head_kernel(const float* __restrict__ pooled,
                            const float* __restrict__ Wm1, const float* __restrict__ bm1,
                            const float* __restrict__ Wm2, const float* __restrict__ bm2,
                            float* __restrict__ out) {
    __shared__ float ts[64][104];
    int tid = threadIdx.x;
    for (int t = tid; t < 64 * 100; t += 256) {
        int b = t / 100, j = t % 100;
        float acc = bm1[j];
        for (int k = 0; k < 64; k++) acc += pooled[b * 64 + k] * Wm1[k * 100 + j];
        ts[b][j] = fmaxf(acc, 0.f);
    }
    __syncthreads();
    if (tid < 64) {
        float acc = bm2[0];
        for (int j = 0; j < 100; j++) acc += ts[tid][j] * Wm2[j];
        out[tid] = acc;
    }
}

extern "C" void kernel_launch(void* const* d_in, const int* in_sizes, int n_in,
                              void* d_out, int out_size, void* d_ws, size_t ws_size,
                              hipStream_t stream) {
    const float* x    = (const float*)d_in[0];
    const float* ea   = (const float*)d_in[1];
    const int*   ei   = (const int*)d_in[2];
    const int*   batch= (const int*)d_in[3];
    const float* W1   = (const float*)d_in[4];
    const float* b1   = (const float*)d_in[5];
    const float* W2   = (const float*)d_in[6];
    const float* b2   = (const float*)d_in[7];
    const float* We   = (const float*)d_in[8];
    const float* be   = (const float*)d_in[9];
    const float* Wp   = (const float*)d_in[10];
    const float* bp   = (const float*)d_in[11];
    const float* Wo   = (const float*)d_in[12];
    const float* bo   = (const float*)d_in[13];
    const float* Wl   = (const float*)d_in[14];
    const float* bl   = (const float*)d_in[15];
    const float* gamma= (const float*)d_in[16];
    const float* beta = (const float*)d_in[17];
    const float* Wm1  = (const float*)d_in[18];
    const float* bm1  = (const float*)d_in[19];
    const float* Wm2  = (const float*)d_in[20];
    const float* bm2  = (const float*)d_in[21];

    float* ws = (float*)d_ws;
    constexpr size_t NF = (size_t)NN * 64;              // 6,400,000
    // all offsets kept multiples of 16 floats (64 B) so eab rows are 32B-aligned
    const size_t o_x2     = 0;
    const size_t o_B      = NF;                         // Bnb bf16 (NF ushorts)
    const size_t o_A      = 2 * NF;
    const size_t o_outpre = 3 * NF;
    const size_t o_start  = 4 * NF;                     // NN+1 uints -> reserve 100016
    const size_t o_cnt_i  = o_start + 100016;           // NN uints (memset 0)
    const size_t o_bsum   = o_cnt_i + 100000;           // 512
    const size_t o_boff   = o_bsum + 512;               // 512
    const size_t o_perm   = o_boff + 512;               // NN ints
    const size_t o_dh     = o_perm + 100000;            // 256 (memset 0)
    const size_t o_doff   = o_dh + 256;                 // 256
    const size_t o_eab    = o_doff + 256;               // (NE+1)*16 bf16 = 12,800,008 floats -> 12,800,016
    const size_t o_srcs   = o_eab + 12800016;           // NE+1 ints -> 1,600,016
    const size_t o_Wtb    = o_srcs + 1600016;           // 64*832 bf16 = 26,624 floats
    const size_t o_Wepp   = o_Wtb + 26624;              // 512 uints
    const size_t o_bpF    = o_Wepp + 512;
    const size_t o_boF    = o_bpF + 64;
    const size_t o_bnscale= o_boF + 64;
    const size_t o_bnshift= o_bnscale + 64;
    const size_t o_pooled = o_bnshift + 64;             // zero block: pooled + bnsum + bnsum2
    const size_t o_bnsum  = o_pooled + 64 * 64;
    const size_t o_bnsum2 = o_bnsum + 64;

    hipMemsetAsync(ws + o_cnt_i, 0, 100000 * sizeof(unsigned), stream);
    hipMemsetAsync(ws + o_dh, 0, 256 * sizeof(unsigned), stream);
    hipMemsetAsync(ws + o_pooled, 0, (64 * 64 + 128) * sizeof(float), stream);

    fold_weights<<<213, 256, 0, stream>>>(Wo, Wl, bo, bl, We, Wp, bp, be,
                                          (__hip_bfloat16*)(ws + o_Wtb), (unsigned*)(ws + o_Wepp),
                                          ws + o_bpF, ws + o_boF);
    node_pre<<<1024, 256, 0, stream>>>(x, W1, b1, W2, b2, Wp,
                                       ws + o_x2, ws + o_A, (__hip_bfloat16*)(ws + o_B));
    hist_kernel<<<6250, 256, 0, stream>>>(ei, (unsigned*)(ws + o_cnt_i));
    scan_blocksum<<<NSCAN_BLOCKS, 256, 0, stream>>>((unsigned*)(ws + o_cnt_i), (unsigned*)(ws + o_bsum));
    scan_top<<<1, 512, 0, stream>>>((unsigned*)(ws + o_bsum), (unsigned*)(ws + o_boff),
                                    (unsigned*)(ws + o_start));
    scan_final<<<NSCAN_BLOCKS, 256, 0, stream>>>((unsigned*)(ws + o_cnt_i), (unsigned*)(ws + o_boff),
                                                 (unsigned*)(ws + o_start));
    deg_hist<<<NSCAN_BLOCKS, 256, 0, stream>>>((const unsigned*)(ws + o_start), (unsigned*)(ws + o_dh));
    deg_scan<<<1, 256, 0, stream>>>((const unsigned*)(ws + o_dh), (unsigned*)(ws + o_doff));
    deg_scatter<<<NSCAN_BLOCKS, 256, 0, stream>>>((const unsigned*)(ws + o_start), (unsigned*)(ws + o_doff),
                                                  (int*)(ws + o_perm));
    scatter_kernel<<<6250, 256, 0, stream>>>(ei, ea, (const unsigned*)(ws + o_start),
                                             (unsigned*)(ws + o_cnt_i),
                                             (__hip_bfloat16*)(ws + o_eab), (int*)(ws + o_srcs));
    agg_post_kernel<<<6250, 256, 0, stream>>>((const __hip_bfloat16*)(ws + o_eab),
                                              (const int*)(ws + o_srcs),
                                              (const unsigned*)(ws + o_start),
                                              (const int*)(ws + o_perm),
                                              ws + o_A, (const unsigned short*)(ws + o_B), ws + o_x2,
                                              (const unsigned*)(ws + o_Wepp), ws + o_bpF,
                                              (const __hip_bfloat16*)(ws + o_Wtb), ws + o_boF,
                                              ws + o_outpre, ws + o_bnsum, ws + o_bnsum2);
    bn_finalize<<<1, 64, 0, stream>>>(ws + o_bnsum, ws + o_bnsum2, gamma, beta,
                                      ws + o_bnscale, ws + o_bnshift);
    bn_pool<<<1563, 256, 0, stream>>>(ws + o_outpre, batch,
                                      ws + o_bnscale, ws + o_bnshift, ws + o_pooled);
    head_kernel<<<1, 256, 0, stream>>>(ws + o_pooled, Wm1, bm1, Wm2, bm2, (float*)d_out);
}

// Round 4
// 813.320 us; speedup vs baseline: 1.4776x; 1.4776x over previous
//
#include <hip/hip_runtime.h>
#include <hip/hip_bf16.h>
#include <math.h>

#define NN 100000
#define NE 1600000
#define FF 64
#define NB 64
#define NSCAN_BLOCKS 391   // ceil(NN/256)

// avg_deg['log'] = sum(log(i+1)*DEG[i]) / sum(DEG)
__device__ __constant__ float AVG_LOG_F = 1.9595436f;

typedef short short8 __attribute__((ext_vector_type(8)));
typedef float f32x4 __attribute__((ext_vector_type(4)));

__device__ __forceinline__ void atomAddF(float* p, float v) {
    __hip_atomic_fetch_add(p, v, __ATOMIC_RELAXED, __HIP_MEMORY_SCOPE_AGENT);
}
__device__ __forceinline__ float bf2f(short v) {
    return __uint_as_float(((unsigned)(unsigned short)v) << 16);
}
__device__ __forceinline__ unsigned packbf2(float a, float b) {
    unsigned ua = (unsigned)(unsigned short)__bfloat16_as_short(__float2bfloat16(a));
    unsigned ub = (unsigned)(unsigned short)__bfloat16_as_short(__float2bfloat16(b));
    return ua | (ub << 16);
}
// D = a.lo*b.lo + a.hi*b.hi + c  (bf16 pairs, f32 accumulate)
__device__ __forceinline__ float dot2bf(unsigned a, unsigned b, float c) {
    float d;
    asm("v_dot2_f32_bf16 %0, %1, %2, %3" : "=v"(d) : "v"(a), "v"(b), "v"(c));
    return d;
}

// ---------------- fold weights: Wtb = (Wo@Wl)^T bf16; Wepp = packed-bf16 (We@Wp2); biases ----------------
__global__ void fold_weights(const float* __restrict__ Wo, const float* __restrict__ Wl,
                             const float* __restrict__ bo, const float* __restrict__ bl,
                             const float* __restrict__ We, const float* __restrict__ Wp,
                             const float* __restrict__ bp, const float* __restrict__ be,
                             __hip_bfloat16* __restrict__ Wtb,   // [64][832]  Wtb[f][k] = (Wo@Wl)[k][f]
                             unsigned* __restrict__ Wepp,        // [8][64] packed bf16 pairs of Wep[k][f]
                             float* __restrict__ bpF, float* __restrict__ boF) {
    int t = blockIdx.x * blockDim.x + threadIdx.x;
    if (t < 832 * 64) {
        int k = t >> 6, f = t & 63;
        float acc = 0.f;
        for (int j = 0; j < 64; j++) acc += Wo[k * 64 + j] * Wl[j * 64 + f];
        Wtb[f * 832 + k] = __float2bfloat16(acc);
    } else if (t < 832 * 64 + 512) {
        int u = t - 832 * 64; int k2 = u >> 6, f = u & 63;
        float a0 = 0.f, a1 = 0.f;
        for (int j = 0; j < 64; j++) {
            float wp = Wp[(128 + j) * 64 + f];
            a0 += We[(2 * k2) * 64 + j] * wp;
            a1 += We[(2 * k2 + 1) * 64 + j] * wp;
        }
        Wepp[k2 * 64 + f] = packbf2(a0, a1);
    } else if (t < 832 * 64 + 512 + 64) {
        int f = t - (832 * 64 + 512);
        float acc = bl[f];
        for (int j = 0; j < 64; j++) acc += bo[j] * Wl[j * 64 + f];
        boF[f] = acc;
    } else if (t < 832 * 64 + 512 + 128) {
        int f = t - (832 * 64 + 512 + 64);
        float acc = bp[f];
        for (int j = 0; j < 64; j++) acc += be[j] * Wp[(128 + j) * 64 + f];
        bpF[f] = acc;
    }
}

// ---------------- node pre-MLP + A/B projections (wave per node); Bn stored bf16 ----------------
__global__ __launch_bounds__(256) void node_pre(const float* __restrict__ x,
                                                const float* __restrict__ W1, const float* __restrict__ b1,
                                                const float* __restrict__ W2, const float* __restrict__ b2,
                                                const float* __restrict__ Wp,
                                                float* __restrict__ x2, float* __restrict__ A,
                                                __hip_bfloat16* __restrict__ Bnb) {
    __shared__ float W1s[64 * 32], W2s[32 * 64], Wp0s[64 * 64], Wp1s[64 * 64];
    __shared__ float xs[4][64], ts[4][32], x2s[4][64];
    int tid = threadIdx.x;
    for (int i = tid; i < 2048; i += 256) W1s[i] = W1[i];
    for (int i = tid; i < 2048; i += 256) W2s[i] = W2[i];
    for (int i = tid; i < 4096; i += 256) Wp0s[i] = Wp[i];
    for (int i = tid; i < 4096; i += 256) Wp1s[i] = Wp[4096 + i];
    __syncthreads();
    int w = tid >> 6, f = tid & 63;
    int wid = blockIdx.x * 4 + w;
    int nw = gridDim.x * 4;
    for (int v = wid; v < NN; v += nw) {
        xs[w][f] = x[(size_t)v * 64 + f];
        if (f < 32) {
            float tj = b1[f];
            for (int k = 0; k < 64; k++) tj += xs[w][k] * W1s[k * 32 + f];
            ts[w][f] = fmaxf(tj, 0.f);
        }
        float acc2 = b2[f];
        for (int k = 0; k < 32; k++) acc2 += ts[w][k] * W2s[k * 64 + f];
        x2s[w][f] = acc2;
        x2[(size_t)v * 64 + f] = acc2;
        float aa = 0.f, bb = 0.f;
        for (int k = 0; k < 64; k++) {
            float xv = x2s[w][k];
            aa += xv * Wp0s[k * 64 + f];
            bb += xv * Wp1s[k * 64 + f];
        }
        A[(size_t)v * 64 + f] = aa;
        Bnb[(size_t)v * 64 + f] = __float2bfloat16(bb);
    }
}

// ---------------- counting sort of edges by dst ----------------
__global__ void hist_kernel(const int* __restrict__ ei, unsigned* __restrict__ cnt_i) {
    int t = blockIdx.x * blockDim.x + threadIdx.x;
    if (t < NE) atomicAdd(&cnt_i[ei[NE + t]], 1u);
}

__global__ void scan_blocksum(const unsigned* __restrict__ cnt_i, unsigned* __restrict__ bsum) {
    __shared__ unsigned red[256];
    int t = blockIdx.x * 256 + threadIdx.x;
    unsigned c = (t < NN) ? cnt_i[t] : 0u;
    red[threadIdx.x] = c; __syncthreads();
    for (int s = 128; s > 0; s >>= 1) {
        if (threadIdx.x < s) red[threadIdx.x] += red[threadIdx.x + s];
        __syncthreads();
    }
    if (threadIdx.x == 0) bsum[blockIdx.x] = red[0];
}

__global__ void scan_top(const unsigned* __restrict__ bsum, unsigned* __restrict__ boff,
                         unsigned* __restrict__ start) {
    __shared__ unsigned sh[512];
    int t = threadIdx.x;
    unsigned v = (t < NSCAN_BLOCKS) ? bsum[t] : 0u;
    sh[t] = v; __syncthreads();
    for (int d = 1; d < 512; d <<= 1) {
        unsigned add = (t >= d) ? sh[t - d] : 0u;
        __syncthreads();
        sh[t] += add;
        __syncthreads();
    }
    if (t < NSCAN_BLOCKS) boff[t] = sh[t] - v;   // exclusive
    if (t == 0) start[NN] = NE;
}

__global__ void scan_final(const unsigned* __restrict__ cnt_i, const unsigned* __restrict__ boff,
                           unsigned* __restrict__ start) {
    __shared__ unsigned sh[256];
    int b = blockIdx.x, t = threadIdx.x;
    int v = b * 256 + t;
    unsigned c = (v < NN) ? cnt_i[v] : 0u;
    sh[t] = c; __syncthreads();
    for (int d = 1; d < 256; d <<= 1) {
        unsigned add = (t >= d) ? sh[t - d] : 0u;
        __syncthreads();
        sh[t] += add;
        __syncthreads();
    }
    if (v < NN) start[v] = boff[b] + sh[t] - c;  // exclusive scan
}

// scatter: materialize sorted edge payloads (src and bf16 edge_attr); pads element NE
__global__ void scatter_kernel(const int* __restrict__ ei, const float* __restrict__ ea,
                               const unsigned* __restrict__ start,
                               unsigned* __restrict__ cnt_i,
                               __hip_bfloat16* __restrict__ eab, int* __restrict__ src_s) {
    int t = blockIdx.x * blockDim.x + threadIdx.x;
    if (t == 0) {
        src_s[NE] = 0;
        short8 z = {0, 0, 0, 0, 0, 0, 0, 0};
        short8* p = (short8*)(eab + (size_t)NE * 16);
        p[0] = z; p[1] = z;
    }
    if (t < NE) {
        int d = ei[NE + t];
        unsigned old = atomicSub(&cnt_i[d], 1u);
        unsigned pos = start[d] + old - 1u;
        src_s[pos] = ei[t];
        const float4* s4 = (const float4*)(ea + (size_t)t * 16);
        float4 a = s4[0], b = s4[1], c = s4[2], e = s4[3];
        short8 o0, o1;
        o0[0] = (short)__bfloat16_as_short(__float2bfloat16(a.x));
        o0[1] = (short)__bfloat16_as_short(__float2bfloat16(a.y));
        o0[2] = (short)__bfloat16_as_short(__float2bfloat16(a.z));
        o0[3] = (short)__bfloat16_as_short(__float2bfloat16(a.w));
        o0[4] = (short)__bfloat16_as_short(__float2bfloat16(b.x));
        o0[5] = (short)__bfloat16_as_short(__float2bfloat16(b.y));
        o0[6] = (short)__bfloat16_as_short(__float2bfloat16(b.z));
        o0[7] = (short)__bfloat16_as_short(__float2bfloat16(b.w));
        o1[0] = (short)__bfloat16_as_short(__float2bfloat16(c.x));
        o1[1] = (short)__bfloat16_as_short(__float2bfloat16(c.y));
        o1[2] = (short)__bfloat16_as_short(__float2bfloat16(c.z));
        o1[3] = (short)__bfloat16_as_short(__float2bfloat16(c.w));
        o1[4] = (short)__bfloat16_as_short(__float2bfloat16(e.x));
        o1[5] = (short)__bfloat16_as_short(__float2bfloat16(e.y));
        o1[6] = (short)__bfloat16_as_short(__float2bfloat16(e.z));
        o1[7] = (short)__bfloat16_as_short(__float2bfloat16(e.w));
        short8* dst8 = (short8*)(eab + (size_t)pos * 16);
        dst8[0] = o0; dst8[1] = o1;
    }
}

// ---------------- degree-sorted node permutation: ZERO atomics, fully deterministic ----------------
// K1: per-block histogram + stable local ranks via plain LDS loops.
__global__ __launch_bounds__(256) void deg_localhist(const unsigned* __restrict__ start,
                                                     unsigned* __restrict__ bh,      // [256][NSCAN_BLOCKS]
                                                     unsigned* __restrict__ rank_g) {
    __shared__ unsigned short keys[256];
    int t0 = threadIdx.x, b = blockIdx.x;
    int t = b * 256 + t0;
    unsigned d = 0xFFFFu;                      // sentinel: matches no bin
    if (t < NN) {
        d = start[t + 1] - start[t];
        if (d > 255u) d = 255u;
    }
    keys[t0] = (unsigned short)d;
    __syncthreads();
    // thread t0 owns bin t0: count occurrences in this block
    unsigned cnt = 0;
    #pragma unroll 8
    for (int i = 0; i < 256; ++i) cnt += (keys[i] == (unsigned short)t0) ? 1u : 0u;
    bh[t0 * NSCAN_BLOCKS + b] = cnt;
    // stable rank of this node among earlier same-bin nodes in the block
    if (t < NN) {
        unsigned r = 0;
        for (int i = 0; i < t0; ++i) r += (keys[i] == (unsigned short)d) ? 1u : 0u;
        rank_g[t] = r;
    }
}

// K2: one block, 256 threads (one per bin). Per-bin totals -> exclusive bin scan ->
// running per-(bin,block) offsets. All plain loads/stores.
__global__ __launch_bounds__(256) void deg_colscan(const unsigned* __restrict__ bh,
                                                   unsigned* __restrict__ bhoff) {
    __shared__ unsigned sh[256];
    int bin = threadIdx.x;
    unsigned s = 0;
    for (int b = 0; b < NSCAN_BLOCKS; ++b) s += bh[bin * NSCAN_BLOCKS + b];
    sh[bin] = s;
    __syncthreads();
    for (int d = 1; d < 256; d <<= 1) {
        unsigned add = (bin >= d) ? sh[bin - d] : 0u;
        __syncthreads();
        sh[bin] += add;
        __syncthreads();
    }
    unsigned run = sh[bin] - s;   // exclusive bin offset
    for (int b = 0; b < NSCAN_BLOCKS; ++b) {
        unsigned c = bh[bin * NSCAN_BLOCKS + b];
        bhoff[bin * NSCAN_BLOCKS + b] = run;
        run += c;
    }
}

// K3: place nodes. perm is an exact permutation of [0,NN), sorted by clamped degree.
__global__ __launch_bounds__(256) void deg_place(const unsigned* __restrict__ start,
                                                 const unsigned* __restrict__ bhoff,
                                                 const unsigned* __restrict__ rank_g,
                                                 int* __restrict__ perm) {
    int t0 = threadIdx.x, b = blockIdx.x;
    int t = b * 256 + t0;
    if (t < NN) {
        unsigned d = start[t + 1] - start[t];
        if (d > 255u) d = 255u;
        perm[bhoff[d * NSCAN_BLOCKS + b] + rank_g[t]] = t;
    }
}

// ---------------- fused aggregation + post GEMM (MFMA) + BN stats ----------------
// block = 256 = 4 waves = 16 nodes, chosen via degree-sorted perm so the 16 nodes
// have near-equal degree (kills maxlen padding). All segment indices/pointers are
// wave-uniform via readfirstlane -> scalar/saddr loads, zero per-lane address math.
// e-dot uses v_dot2_f32_bf16 against pre-packed bf16 Wep pairs (no bf16 decode).
__global__ __launch_bounds__(256) void agg_post_kernel(const __hip_bfloat16* __restrict__ eab,
                                                       const int* __restrict__ src_s,
                                                       const unsigned* __restrict__ start,
                                                       const int* __restrict__ perm,
                                                       const float* __restrict__ A,
                                                       const unsigned short* __restrict__ Bnb,
                                                       const float* __restrict__ x2,
                                                       const unsigned* __restrict__ Wepp, const float* __restrict__ bpF,
                                                       const __hip_bfloat16* __restrict__ Wtb,
                                                       const float* __restrict__ boF,
                                                       float* __restrict__ out_pre,
                                                       float* __restrict__ bnsum, float* __restrict__ bnsum2) {
    __shared__ __hip_bfloat16 As[16 * 840];
    __shared__ int pvs[16];
    int tid = threadIdx.x;
    int w = __builtin_amdgcn_readfirstlane(tid >> 6);   // wave id, force SGPR
    int f = tid & 63;
    int base = blockIdx.x * 16;      // 6250 blocks exactly

    unsigned wcolp[8];
    #pragma unroll
    for (int k = 0; k < 8; k++) wcolp[k] = Wepp[k * 64 + f];
    float bpf = bpF[f];

    int vv[4]; unsigned s0[4]; int len[4], lim[4]; float av[4];
    float sA[4] = {0.f, 0.f, 0.f, 0.f}, s2A[4] = {0.f, 0.f, 0.f, 0.f};
    float mnA[4], mxA[4];
    int maxlen = 0;
    #pragma unroll
    for (int g = 0; g < 4; ++g) {
        int v = __builtin_amdgcn_readfirstlane(perm[base + g * 4 + w]);
        vv[g] = v;
        if (f == 0) pvs[g * 4 + w] = v;
        unsigned a = start[v], b = start[v + 1];
        s0[g] = a; len[g] = (int)(b - a);
        lim[g] = len[g] > 0 ? len[g] - 1 : 0;
        maxlen = max(maxlen, len[g]);
        av[g] = A[(size_t)v * 64 + f] + bpf;
        mnA[g] = INFINITY; mxA[g] = -INFINITY;
    }

    for (int j = 0; j < maxlen; ++j) {
        #pragma unroll
        for (int g = 0; g < 4; ++g) {
            unsigned idx = s0[g] + (unsigned)min(j, lim[g]);   // wave-uniform
            const unsigned* e32 = (const unsigned*)(eab + (size_t)idx * 16);
            int src = src_s[idx];                               // wave-uniform
            const unsigned short* brow = Bnb + ((size_t)src << 6);
            float h = av[g];
            #pragma unroll
            for (int k = 0; k < 8; k++) h = dot2bf(e32[k], wcolp[k], h);
            h += bf2f((short)brow[f]);                          // SGPR base + f*2 voffset
            bool valid = j < len[g];
            float hm = valid ? h : 0.f;
            sA[g] += hm; s2A[g] += hm * hm;
            // clamped duplicates are idempotent for min/max; deg-0 fixed by `has` below
            mnA[g] = fminf(mnA[g], h);
            mxA[g] = fmaxf(mxA[g], h);
        }
    }

    #pragma unroll
    for (int g = 0; g < 4; ++g) {
        int n = g * 4 + w;
        int v = vv[g];
        float c = (float)len[g];
        float d = fmaxf(c, 1.f);
        float inv = 1.f / d;
        float mean = sA[g] * inv, mean2 = s2A[g] * inv;
        float sd = sqrtf(fmaxf(mean2 - mean * mean, 0.f) + 1e-5f);
        bool has = len[g] > 0;
        float mn = has ? mnA[g] : 0.f;
        float mx = has ? mxA[g] : 0.f;
        float l = __logf(d + 1.f);
        float amp = l * (1.0f / 1.9595436f);
        float iamp = 1.9595436f / l;
        __hip_bfloat16* row = &As[n * 840];
        row[f]        = __float2bfloat16(x2[(size_t)v * 64 + f]);
        row[64 + f]   = __float2bfloat16(mean);
        row[128 + f]  = __float2bfloat16(mn);
        row[192 + f]  = __float2bfloat16(mx);
        row[256 + f]  = __float2bfloat16(sd);
        row[320 + f]  = __float2bfloat16(mean * amp);
        row[384 + f]  = __float2bfloat16(mn * amp);
        row[448 + f]  = __float2bfloat16(mx * amp);
        row[512 + f]  = __float2bfloat16(sd * amp);
        row[576 + f]  = __float2bfloat16(mean * iamp);
        row[640 + f]  = __float2bfloat16(mn * iamp);
        row[704 + f]  = __float2bfloat16(mx * iamp);
        row[768 + f]  = __float2bfloat16(sd * iamp);
    }
    __syncthreads();

    // MFMA phase: lane = m + 16q; A[m][k=q*8+j], B[k][n=m]; D: col=lane&15, row=q*4+reg
    int m = f & 15, q = f >> 4;
    int fbase = w * 16;
    f32x4 acc = {0.f, 0.f, 0.f, 0.f};
    const __hip_bfloat16* arow = &As[m * 840 + q * 8];
    const __hip_bfloat16* brow = &Wtb[(size_t)(fbase + m) * 832 + q * 8];
    #pragma unroll
    for (int s = 0; s < 26; ++s) {
        short8 af = *(const short8*)(arow + s * 32);
        short8 bf = *(const short8*)(brow + s * 32);
        acc = __builtin_amdgcn_mfma_f32_16x16x32_bf16(af, bf, acc, 0, 0, 0);
    }

    float bof = boF[fbase + m];
    float p1 = 0.f, p2 = 0.f;
    #pragma unroll
    for (int r = 0; r < 4; ++r) {
        float vvv = acc[r] + bof;
        int vn = pvs[q * 4 + r];
        out_pre[(size_t)vn * 64 + fbase + m] = vvv;
        p1 += vvv; p2 += vvv * vvv;
    }
    p1 += __shfl_xor(p1, 16); p2 += __shfl_xor(p2, 16);
    p1 += __shfl_xor(p1, 32); p2 += __shfl_xor(p2, 32);
    if (f < 16) {
        atomAddF(&bnsum[fbase + f], p1);
        atomAddF(&bnsum2[fbase + f], p2);
    }
}

// ---------------- BN finalize ----------------
__global__ void bn_finalize(const float* __restrict__ bnsum, const float* __restrict__ bnsum2,
                            const float* __restrict__ gamma, const float* __restrict__ beta,
                            float* __restrict__ bnscale, float* __restrict__ bnshift) {
    int f = threadIdx.x;
    if (f < 64) {
        float mu = bnsum[f] * (1.0f / NN);
        float var = bnsum2[f] * (1.0f / NN) - mu * mu;
        float sc = gamma[f] / sqrtf(var + 1e-5f);
        bnscale[f] = sc;
        bnshift[f] = beta[f] - mu * sc;
    }
}

// ---------------- BN apply + ReLU + global_add_pool ----------------
__global__ __launch_bounds__(256) void bn_pool(const float* __restrict__ out_pre, const int* __restrict__ batch,
                                               const float* __restrict__ bnscale, const float* __restrict__ bnshift,
                                               float* __restrict__ pooled) {
    __shared__ float red[256];
    int tid = threadIdx.x, f = tid & 63, q = tid >> 6;
    int base = blockIdx.x * 64;
    float sc = bnscale[f], sh = bnshift[f];
    int b_first = batch[base < NN ? base : NN - 1];
    int last = base + 63; if (last >= NN) last = NN - 1;
    int b_last = batch[last];
    if (b_first == b_last) {
        float local = 0.f;
        for (int g = 0; g < 16; ++g) {
            int v = base + g * 4 + q;
            if (v < NN) local += fmaxf(out_pre[(size_t)v * 64 + f] * sc + sh, 0.f);
        }
        red[tid] = local;
        __syncthreads();
        if (tid < 64) atomAddF(&pooled[b_first * 64 + f], red[f] + red[f + 64] + red[f + 128] + red[f + 192]);
    } else {
        for (int g = 0; g < 16; ++g) {
            int v = base + g * 4 + q;
            if (v < NN) {
                float val = fmaxf(out_pre[(size_t)v * 64 + f] * sc + sh, 0.f);
                atomAddF(&pooled[batch[v] * 64 + f], val);
            }
        }
    }
}

// ---------------- head MLP: relu(pooled@Wm1+bm1)@Wm2+bm2 ----------------
__global__ void head_kernel(const float* __restrict__ pooled,
                            const float* __restrict__ Wm1, const float* __restrict__ bm1,
                            const float* __restrict__ Wm2, const float* __restrict__ bm2,
                            float* __restrict__ out) {
    __shared__ float ts[64][104];
    int tid = threadIdx.x;
    for (int t = tid; t < 64 * 100; t += 256) {
        int b = t / 100, j = t % 100;
        float acc = bm1[j];
        for (int k = 0; k < 64; k++) acc += pooled[b * 64 + k] * Wm1[k * 100 + j];
        ts[b][j] = fmaxf(acc, 0.f);
    }
    __syncthreads();
    if (tid < 64) {
        float acc = bm2[0];
        for (int j = 0; j < 100; j++) acc += ts[tid][j] * Wm2[j];
        out[tid] = acc;
    }
}

extern "C" void kernel_launch(void* const* d_in, const int* in_sizes, int n_in,
                              void* d_out, int out_size, void* d_ws, size_t ws_size,
                              hipStream_t stream) {
    const float* x    = (const float*)d_in[0];
    const float* ea   = (const float*)d_in[1];
    const int*   ei   = (const int*)d_in[2];
    const int*   batch= (const int*)d_in[3];
    const float* W1   = (const float*)d_in[4];
    const float* b1   = (const float*)d_in[5];
    const float* W2   = (const float*)d_in[6];
    const float* b2   = (const float*)d_in[7];
    const float* We   = (const float*)d_in[8];
    const float* be   = (const float*)d_in[9];
    const float* Wp   = (const float*)d_in[10];
    const float* bp   = (const float*)d_in[11];
    const float* Wo   = (const float*)d_in[12];
    const float* bo   = (const float*)d_in[13];
    const float* Wl   = (const float*)d_in[14];
    const float* bl   = (const float*)d_in[15];
    const float* gamma= (const float*)d_in[16];
    const float* beta = (const float*)d_in[17];
    const float* Wm1  = (const float*)d_in[18];
    const float* bm1  = (const float*)d_in[19];
    const float* Wm2  = (const float*)d_in[20];
    const float* bm2  = (const float*)d_in[21];

    float* ws = (float*)d_ws;
    constexpr size_t NF = (size_t)NN * 64;              // 6,400,000
    // all offsets kept multiples of 16 floats (64 B) so eab rows are 32B-aligned
    const size_t o_x2     = 0;
    const size_t o_B      = NF;                         // Bnb bf16 (NF ushorts)
    const size_t o_A      = 2 * NF;
    const size_t o_outpre = 3 * NF;
    const size_t o_start  = 4 * NF;                     // NN+1 uints -> reserve 100016
    const size_t o_cnt_i  = o_start + 100016;           // NN uints (memset 0)
    const size_t o_bsum   = o_cnt_i + 100000;           // 512
    const size_t o_boff   = o_bsum + 512;               // 512
    const size_t o_perm   = o_boff + 512;               // NN ints
    const size_t o_eab    = o_perm + 100000;            // (NE+1)*16 bf16 = 12,800,008 floats -> 12,800,016
    const size_t o_srcs   = o_eab + 12800016;           // NE+1 ints -> 1,600,016
    const size_t o_Wtb    = o_srcs + 1600016;           // 64*832 bf16 = 26,624 floats
    const size_t o_Wepp   = o_Wtb + 26624;              // 512 uints
    const size_t o_bpF    = o_Wepp + 512;
    const size_t o_boF    = o_bpF + 64;
    const size_t o_bnscale= o_boF + 64;
    const size_t o_bnshift= o_bnscale + 64;
    const size_t o_pooled = o_bnshift + 64;             // zero block: pooled + bnsum + bnsum2
    const size_t o_bnsum  = o_pooled + 64 * 64;
    const size_t o_bnsum2 = o_bnsum + 64;

    // Aliased scratch (no extra workspace):
    //  bh    [256][391] uints -> reuses cnt_i+bsum+boff (101,024 >= 100,096), dead after scatter_kernel
    //  bhoff [256][391] uints -> front of out_pre (dead until agg_post)
    //  rank_g [NN] uints      -> out_pre + 100,096
    unsigned* bh     = (unsigned*)(ws + o_cnt_i);
    unsigned* bhoff  = (unsigned*)(ws + o_outpre);
    unsigned* rank_g = (unsigned*)(ws + o_outpre + 100096);

    hipMemsetAsync(ws + o_cnt_i, 0, 100000 * sizeof(unsigned), stream);
    hipMemsetAsync(ws + o_pooled, 0, (64 * 64 + 128) * sizeof(float), stream);

    fold_weights<<<213, 256, 0, stream>>>(Wo, Wl, bo, bl, We, Wp, bp, be,
                                          (__hip_bfloat16*)(ws + o_Wtb), (unsigned*)(ws + o_Wepp),
                                          ws + o_bpF, ws + o_boF);
    node_pre<<<1024, 256, 0, stream>>>(x, W1, b1, W2, b2, Wp,
                                       ws + o_x2, ws + o_A, (__hip_bfloat16*)(ws + o_B));
    hist_kernel<<<6250, 256, 0, stream>>>(ei, (unsigned*)(ws + o_cnt_i));
    scan_blocksum<<<NSCAN_BLOCKS, 256, 0, stream>>>((unsigned*)(ws + o_cnt_i), (unsigned*)(ws + o_bsum));
    scan_top<<<1, 512, 0, stream>>>((unsigned*)(ws + o_bsum), (unsigned*)(ws + o_boff),
                                    (unsigned*)(ws + o_start));
    scan_final<<<NSCAN_BLOCKS, 256, 0, stream>>>((unsigned*)(ws + o_cnt_i), (unsigned*)(ws + o_boff),
                                                 (unsigned*)(ws + o_start));
    scatter_kernel<<<6250, 256, 0, stream>>>(ei, ea, (const unsigned*)(ws + o_start),
                                             (unsigned*)(ws + o_cnt_i),
                                             (__hip_bfloat16*)(ws + o_eab), (int*)(ws + o_srcs));
    // degree-sort pipeline (after scatter frees cnt_i region; before agg_post clobbers out_pre)
    deg_localhist<<<NSCAN_BLOCKS, 256, 0, stream>>>((const unsigned*)(ws + o_start), bh, rank_g);
    deg_colscan<<<1, 256, 0, stream>>>(bh, bhoff);
    deg_place<<<NSCAN_BLOCKS, 256, 0, stream>>>((const unsigned*)(ws + o_start), bhoff, rank_g,
                                                (int*)(ws + o_perm));
    agg_post_kernel<<<6250, 256, 0, stream>>>((const __hip_bfloat16*)(ws + o_eab),
                                              (const int*)(ws + o_srcs),
                                              (const unsigned*)(ws + o_start),
                                              (const int*)(ws + o_perm),
                                              ws + o_A, (const unsigned short*)(ws + o_B), ws + o_x2,
                                              (const unsigned*)(ws + o_Wepp), ws + o_bpF,
                                              (const __hip_bfloat16*)(ws + o_Wtb), ws + o_boF,
                                              ws + o_outpre, ws + o_bnsum, ws + o_bnsum2);
    bn_finalize<<<1, 64, 0, stream>>>(ws + o_bnsum, ws + o_bnsum2, gamma, beta,
                                      ws + o_bnscale, ws + o_bnshift);
    bn_pool<<<1563, 256, 0, stream>>>(ws + o_outpre, batch,
                                      ws + o_bnscale, ws + o_bnshift, ws + o_pooled);
    head_kernel<<<1, 256, 0, stream>>>(ws + o_pooled, Wm1, bm1, Wm2, bm2, (float*)d_out);
}

// Round 6
// 733.781 us; speedup vs baseline: 1.6378x; 1.1084x over previous
//
#include <hip/hip_runtime.h>
#include <hip/hip_bf16.h>
#include <math.h>

#define NN 100000
#define NE 1600000
#define FF 64
#define NB 64
#define NSCAN_BLOCKS 391   // ceil(NN/256)

// avg_deg['log'] = sum(log(i+1)*DEG[i]) / sum(DEG)
__device__ __constant__ float AVG_LOG_F = 1.9595436f;

typedef short short8 __attribute__((ext_vector_type(8)));
typedef float f32x4 __attribute__((ext_vector_type(4)));

__device__ __forceinline__ void atomAddF(float* p, float v) {
    __hip_atomic_fetch_add(p, v, __ATOMIC_RELAXED, __HIP_MEMORY_SCOPE_AGENT);
}
__device__ __forceinline__ float bf2f(short v) {
    return __uint_as_float(((unsigned)(unsigned short)v) << 16);
}
__device__ __forceinline__ unsigned packbf2(float a, float b) {
    unsigned ua = (unsigned)(unsigned short)__bfloat16_as_short(__float2bfloat16(a));
    unsigned ub = (unsigned)(unsigned short)__bfloat16_as_short(__float2bfloat16(b));
    return ua | (ub << 16);
}
// legal may-alias dword load of two adjacent u16 LDS elements (avoids TBAA UB:
// u16 stores + u32 cast-loads let the compiler hoist loads above the stores)
__device__ __forceinline__ unsigned lds_pair(const unsigned short* p) {
    unsigned u;
    __builtin_memcpy(&u, p, 4);
    return u;
}
// D = a.lo*b.lo + a.hi*b.hi + c  (bf16 pairs, f32 accumulate)
__device__ __forceinline__ float dot2bf(unsigned a, unsigned b, float c) {
    float d;
    asm("v_dot2_f32_bf16 %0, %1, %2, %3" : "=v"(d) : "v"(a), "v"(b), "v"(c));
    return d;
}

// ---------------- fold weights: Wtb = (Wo@Wl)^T bf16; Wepp = packed-bf16 (We@Wp2); biases ----------------
__global__ void fold_weights(const float* __restrict__ Wo, const float* __restrict__ Wl,
                             const float* __restrict__ bo, const float* __restrict__ bl,
                             const float* __restrict__ We, const float* __restrict__ Wp,
                             const float* __restrict__ bp, const float* __restrict__ be,
                             __hip_bfloat16* __restrict__ Wtb,   // [64][832]  Wtb[f][k] = (Wo@Wl)[k][f]
                             unsigned* __restrict__ Wepp,        // [8][64] packed bf16 pairs of Wep[k][f]
                             float* __restrict__ bpF, float* __restrict__ boF) {
    int t = blockIdx.x * blockDim.x + threadIdx.x;
    if (t < 832 * 64) {
        int k = t >> 6, f = t & 63;
        float acc = 0.f;
        for (int j = 0; j < 64; j++) acc += Wo[k * 64 + j] * Wl[j * 64 + f];
        Wtb[f * 832 + k] = __float2bfloat16(acc);
    } else if (t < 832 * 64 + 512) {
        int u = t - 832 * 64; int k2 = u >> 6, f = u & 63;
        float a0 = 0.f, a1 = 0.f;
        for (int j = 0; j < 64; j++) {
            float wp = Wp[(128 + j) * 64 + f];
            a0 += We[(2 * k2) * 64 + j] * wp;
            a1 += We[(2 * k2 + 1) * 64 + j] * wp;
        }
        Wepp[k2 * 64 + f] = packbf2(a0, a1);
    } else if (t < 832 * 64 + 512 + 64) {
        int f = t - (832 * 64 + 512);
        float acc = bl[f];
        for (int j = 0; j < 64; j++) acc += bo[j] * Wl[j * 64 + f];
        boF[f] = acc;
    } else if (t < 832 * 64 + 512 + 128) {
        int f = t - (832 * 64 + 512 + 64);
        float acc = bp[f];
        for (int j = 0; j < 64; j++) acc += be[j] * Wp[(128 + j) * 64 + f];
        bpF[f] = acc;
    }
}

// ---------------- node pre-MLP + A/B projections: weights in REGISTERS (packed bf16),
// dot2 math, LDS only as tiny per-wave broadcast buffer. No barriers, no weight LDS.
__global__ __launch_bounds__(256) void node_pre(const float* __restrict__ x,
                                                const float* __restrict__ W1, const float* __restrict__ b1,
                                                const float* __restrict__ W2, const float* __restrict__ b2,
                                                const float* __restrict__ Wp,
                                                float* __restrict__ x2, float* __restrict__ A,
                                                __hip_bfloat16* __restrict__ Bnb) {
    __shared__ unsigned short xs[4][64], ts[4][32], x2s[4][64];
    int tid = threadIdx.x;
    int w = tid >> 6, f = tid & 63;
    int fm = f & 31;

    // hoist all weights into registers as packed bf16 pairs (loop-invariant across nodes)
    unsigned w1p[32], w2p[16], wp0p[32], wp1p[32];
    #pragma unroll
    for (int k2 = 0; k2 < 32; ++k2)
        w1p[k2] = packbf2(W1[(2 * k2) * 32 + fm], W1[(2 * k2 + 1) * 32 + fm]);
    #pragma unroll
    for (int k2 = 0; k2 < 16; ++k2)
        w2p[k2] = packbf2(W2[(2 * k2) * 64 + f], W2[(2 * k2 + 1) * 64 + f]);
    #pragma unroll
    for (int k2 = 0; k2 < 32; ++k2) {
        wp0p[k2] = packbf2(Wp[(2 * k2) * 64 + f], Wp[(2 * k2 + 1) * 64 + f]);
        wp1p[k2] = packbf2(Wp[4096 + (2 * k2) * 64 + f], Wp[4096 + (2 * k2 + 1) * 64 + f]);
    }
    float b1f = b1[fm], b2f = b2[f];

    int wid = blockIdx.x * 4 + w;
    int nw = gridDim.x * 4;
    for (int v = wid; v < NN; v += nw) {
        float xv = x[(size_t)v * 64 + f];
        xs[w][f] = (unsigned short)__bfloat16_as_short(__float2bfloat16(xv));
        float t = b1f;
        #pragma unroll
        for (int k2 = 0; k2 < 32; ++k2) t = dot2bf(lds_pair(&xs[w][2 * k2]), w1p[k2], t);
        t = fmaxf(t, 0.f);
        if (f < 32) ts[w][f] = (unsigned short)__bfloat16_as_short(__float2bfloat16(t));
        float acc2 = b2f;
        #pragma unroll
        for (int k2 = 0; k2 < 16; ++k2) acc2 = dot2bf(lds_pair(&ts[w][2 * k2]), w2p[k2], acc2);
        x2[(size_t)v * 64 + f] = acc2;
        x2s[w][f] = (unsigned short)__bfloat16_as_short(__float2bfloat16(acc2));
        float aa = 0.f, bb = 0.f;
        #pragma unroll
        for (int k2 = 0; k2 < 32; ++k2) {
            unsigned xq = lds_pair(&x2s[w][2 * k2]);
            aa = dot2bf(xq, wp0p[k2], aa);
            bb = dot2bf(xq, wp1p[k2], bb);
        }
        A[(size_t)v * 64 + f] = aa;
        Bnb[(size_t)v * 64 + f] = __float2bfloat16(bb);
    }
}

// ---------------- counting sort of edges by dst ----------------
__global__ void hist_kernel(const int* __restrict__ ei, unsigned* __restrict__ cnt_i) {
    int t = blockIdx.x * blockDim.x + threadIdx.x;
    if (t < NE) atomicAdd(&cnt_i[ei[NE + t]], 1u);
}

__global__ void scan_blocksum(const unsigned* __restrict__ cnt_i, unsigned* __restrict__ bsum) {
    __shared__ unsigned red[256];
    int t = blockIdx.x * 256 + threadIdx.x;
    unsigned c = (t < NN) ? cnt_i[t] : 0u;
    red[threadIdx.x] = c; __syncthreads();
    for (int s = 128; s > 0; s >>= 1) {
        if (threadIdx.x < s) red[threadIdx.x] += red[threadIdx.x + s];
        __syncthreads();
    }
    if (threadIdx.x == 0) bsum[blockIdx.x] = red[0];
}

__global__ void scan_top(const unsigned* __restrict__ bsum, unsigned* __restrict__ boff,
                         unsigned* __restrict__ start) {
    __shared__ unsigned sh[512];
    int t = threadIdx.x;
    unsigned v = (t < NSCAN_BLOCKS) ? bsum[t] : 0u;
    sh[t] = v; __syncthreads();
    for (int d = 1; d < 512; d <<= 1) {
        unsigned add = (t >= d) ? sh[t - d] : 0u;
        __syncthreads();
        sh[t] += add;
        __syncthreads();
    }
    if (t < NSCAN_BLOCKS) boff[t] = sh[t] - v;   // exclusive
    if (t == 0) start[NN] = NE;
}

__global__ void scan_final(const unsigned* __restrict__ cnt_i, const unsigned* __restrict__ boff,
                           unsigned* __restrict__ start) {
    __shared__ unsigned sh[256];
    int b = blockIdx.x, t = threadIdx.x;
    int v = b * 256 + t;
    unsigned c = (v < NN) ? cnt_i[v] : 0u;
    sh[t] = c; __syncthreads();
    for (int d = 1; d < 256; d <<= 1) {
        unsigned add = (t >= d) ? sh[t - d] : 0u;
        __syncthreads();
        sh[t] += add;
        __syncthreads();
    }
    if (v < NN) start[v] = boff[b] + sh[t] - c;  // exclusive scan
}

// scatter: materialize sorted edge payloads (src and bf16 edge_attr); pads element NE
__global__ void scatter_kernel(const int* __restrict__ ei, const float* __restrict__ ea,
                               const unsigned* __restrict__ start,
                               unsigned* __restrict__ cnt_i,
                               __hip_bfloat16* __restrict__ eab, int* __restrict__ src_s) {
    int t = blockIdx.x * blockDim.x + threadIdx.x;
    if (t == 0) {
        src_s[NE] = 0;
        short8 z = {0, 0, 0, 0, 0, 0, 0, 0};
        short8* p = (short8*)(eab + (size_t)NE * 16);
        p[0] = z; p[1] = z;
    }
    if (t < NE) {
        int d = ei[NE + t];
        unsigned old = atomicSub(&cnt_i[d], 1u);
        unsigned pos = start[d] + old - 1u;
        src_s[pos] = ei[t];
        const float4* s4 = (const float4*)(ea + (size_t)t * 16);
        float4 a = s4[0], b = s4[1], c = s4[2], e = s4[3];
        short8 o0, o1;
        o0[0] = (short)__bfloat16_as_short(__float2bfloat16(a.x));
        o0[1] = (short)__bfloat16_as_short(__float2bfloat16(a.y));
        o0[2] = (short)__bfloat16_as_short(__float2bfloat16(a.z));
        o0[3] = (short)__bfloat16_as_short(__float2bfloat16(a.w));
        o0[4] = (short)__bfloat16_as_short(__float2bfloat16(b.x));
        o0[5] = (short)__bfloat16_as_short(__float2bfloat16(b.y));
        o0[6] = (short)__bfloat16_as_short(__float2bfloat16(b.z));
        o0[7] = (short)__bfloat16_as_short(__float2bfloat16(b.w));
        o1[0] = (short)__bfloat16_as_short(__float2bfloat16(c.x));
        o1[1] = (short)__bfloat16_as_short(__float2bfloat16(c.y));
        o1[2] = (short)__bfloat16_as_short(__float2bfloat16(c.z));
        o1[3] = (short)__bfloat16_as_short(__float2bfloat16(c.w));
        o1[4] = (short)__bfloat16_as_short(__float2bfloat16(e.x));
        o1[5] = (short)__bfloat16_as_short(__float2bfloat16(e.y));
        o1[6] = (short)__bfloat16_as_short(__float2bfloat16(e.z));
        o1[7] = (short)__bfloat16_as_short(__float2bfloat16(e.w));
        short8* dst8 = (short8*)(eab + (size_t)pos * 16);
        dst8[0] = o0; dst8[1] = o1;
    }
}

// ---------------- degree-sorted node permutation: ZERO atomics, fully deterministic ----------------
__global__ __launch_bounds__(256) void deg_localhist(const unsigned* __restrict__ start,
                                                     unsigned* __restrict__ bh,      // [256][NSCAN_BLOCKS]
                                                     unsigned* __restrict__ rank_g) {
    __shared__ unsigned short keys[256];
    int t0 = threadIdx.x, b = blockIdx.x;
    int t = b * 256 + t0;
    unsigned d = 0xFFFFu;                      // sentinel: matches no bin
    if (t < NN) {
        d = start[t + 1] - start[t];
        if (d > 255u) d = 255u;
    }
    keys[t0] = (unsigned short)d;
    __syncthreads();
    unsigned cnt = 0;
    #pragma unroll 8
    for (int i = 0; i < 256; ++i) cnt += (keys[i] == (unsigned short)t0) ? 1u : 0u;
    bh[t0 * NSCAN_BLOCKS + b] = cnt;
    if (t < NN) {
        unsigned r = 0;
        for (int i = 0; i < t0; ++i) r += (keys[i] == (unsigned short)d) ? 1u : 0u;
        rank_g[t] = r;
    }
}

__global__ __launch_bounds__(256) void deg_colscan(const unsigned* __restrict__ bh,
                                                   unsigned* __restrict__ bhoff) {
    __shared__ unsigned sh[256];
    int bin = threadIdx.x;
    unsigned s = 0;
    for (int b = 0; b < NSCAN_BLOCKS; ++b) s += bh[bin * NSCAN_BLOCKS + b];
    sh[bin] = s;
    __syncthreads();
    for (int d = 1; d < 256; d <<= 1) {
        unsigned add = (bin >= d) ? sh[bin - d] : 0u;
        __syncthreads();
        sh[bin] += add;
        __syncthreads();
    }
    unsigned run = sh[bin] - s;   // exclusive bin offset
    for (int b = 0; b < NSCAN_BLOCKS; ++b) {
        unsigned c = bh[bin * NSCAN_BLOCKS + b];
        bhoff[bin * NSCAN_BLOCKS + b] = run;
        run += c;
    }
}

__global__ __launch_bounds__(256) void deg_place(const unsigned* __restrict__ start,
                                                 const unsigned* __restrict__ bhoff,
                                                 const unsigned* __restrict__ rank_g,
                                                 int* __restrict__ perm) {
    int t0 = threadIdx.x, b = blockIdx.x;
    int t = b * 256 + t0;
    if (t < NN) {
        unsigned d = start[t + 1] - start[t];
        if (d > 255u) d = 255u;
        perm[bhoff[d * NSCAN_BLOCKS + b] + rank_g[t]] = t;
    }
}

// ---------------- fused aggregation + post GEMM (MFMA) + BN stats ----------------
__global__ __launch_bounds__(256) void agg_post_kernel(const __hip_bfloat16* __restrict__ eab,
                                                       const int* __restrict__ src_s,
                                                       const unsigned* __restrict__ start,
                                                       const int* __restrict__ perm,
                                                       const float* __restrict__ A,
                                                       const unsigned short* __restrict__ Bnb,
                                                       const float* __restrict__ x2,
                                                       const unsigned* __restrict__ Wepp, const float* __restrict__ bpF,
                                                       const __hip_bfloat16* __restrict__ Wtb,
                                                       const float* __restrict__ boF,
                                                       float* __restrict__ out_pre,
                                                       float* __restrict__ bnsum, float* __restrict__ bnsum2) {
    __shared__ __hip_bfloat16 As[16 * 840];
    __shared__ int pvs[16];
    int tid = threadIdx.x;
    int w = __builtin_amdgcn_readfirstlane(tid >> 6);   // wave id, force SGPR
    int f = tid & 63;
    int base = blockIdx.x * 16;      // 6250 blocks exactly

    unsigned wcolp[8];
    #pragma unroll
    for (int k = 0; k < 8; k++) wcolp[k] = Wepp[k * 64 + f];
    float bpf = bpF[f];

    int vv[4]; unsigned s0[4]; int len[4], lim[4]; float av[4];
    float sA[4] = {0.f, 0.f, 0.f, 0.f}, s2A[4] = {0.f, 0.f, 0.f, 0.f};
    float mnA[4], mxA[4];
    int maxlen = 0;
    #pragma unroll
    for (int g = 0; g < 4; ++g) {
        int v = __builtin_amdgcn_readfirstlane(perm[base + g * 4 + w]);
        vv[g] = v;
        if (f == 0) pvs[g * 4 + w] = v;
        unsigned a = start[v], b = start[v + 1];
        s0[g] = a; len[g] = (int)(b - a);
        lim[g] = len[g] > 0 ? len[g] - 1 : 0;
        maxlen = max(maxlen, len[g]);
        av[g] = A[(size_t)v * 64 + f] + bpf;
        mnA[g] = INFINITY; mxA[g] = -INFINITY;
    }

    for (int j = 0; j < maxlen; ++j) {
        #pragma unroll
        for (int g = 0; g < 4; ++g) {
            unsigned idx = s0[g] + (unsigned)min(j, lim[g]);   // wave-uniform
            const unsigned* e32 = (const unsigned*)(eab + (size_t)idx * 16);
            int src = src_s[idx];                               // wave-uniform
            const unsigned short* brow = Bnb + ((size_t)src << 6);
            float h = av[g];
            #pragma unroll
            for (int k = 0; k < 8; k++) h = dot2bf(e32[k], wcolp[k], h);
            h += bf2f((short)brow[f]);                          // SGPR base + f*2 voffset
            bool valid = j < len[g];
            float hm = valid ? h : 0.f;
            sA[g] += hm; s2A[g] += hm * hm;
            mnA[g] = fminf(mnA[g], h);
            mxA[g] = fmaxf(mxA[g], h);
        }
    }

    #pragma unroll
    for (int g = 0; g < 4; ++g) {
        int n = g * 4 + w;
        int v = vv[g];
        float c = (float)len[g];
        float d = fmaxf(c, 1.f);
        float inv = 1.f / d;
        float mean = sA[g] * inv, mean2 = s2A[g] * inv;
        float sd = sqrtf(fmaxf(mean2 - mean * mean, 0.f) + 1e-5f);
        bool has = len[g] > 0;
        float mn = has ? mnA[g] : 0.f;
        float mx = has ? mxA[g] : 0.f;
        float l = __logf(d + 1.f);
        float amp = l * (1.0f / 1.9595436f);
        float iamp = 1.9595436f / l;
        __hip_bfloat16* row = &As[n * 840];
        row[f]        = __float2bfloat16(x2[(size_t)v * 64 + f]);
        row[64 + f]   = __float2bfloat16(mean);
        row[128 + f]  = __float2bfloat16(mn);
        row[192 + f]  = __float2bfloat16(mx);
        row[256 + f]  = __float2bfloat16(sd);
        row[320 + f]  = __float2bfloat16(mean * amp);
        row[384 + f]  = __float2bfloat16(mn * amp);
        row[448 + f]  = __float2bfloat16(mx * amp);
        row[512 + f]  = __float2bfloat16(sd * amp);
        row[576 + f]  = __float2bfloat16(mean * iamp);
        row[640 + f]  = __float2bfloat16(mn * iamp);
        row[704 + f]  = __float2bfloat16(mx * iamp);
        row[768 + f]  = __float2bfloat16(sd * iamp);
    }
    __syncthreads();

    // MFMA phase: lane = m + 16q; A[m][k=q*8+j], B[k][n=m]; D: col=lane&15, row=q*4+reg
    int m = f & 15, q = f >> 4;
    int fbase = w * 16;
    f32x4 acc = {0.f, 0.f, 0.f, 0.f};
    const __hip_bfloat16* arow = &As[m * 840 + q * 8];
    const __hip_bfloat16* brow = &Wtb[(size_t)(fbase + m) * 832 + q * 8];
    #pragma unroll
    for (int s = 0; s < 26; ++s) {
        short8 af = *(const short8*)(arow + s * 32);
        short8 bf = *(const short8*)(brow + s * 32);
        acc = __builtin_amdgcn_mfma_f32_16x16x32_bf16(af, bf, acc, 0, 0, 0);
    }

    float bof = boF[fbase + m];
    float p1 = 0.f, p2 = 0.f;
    #pragma unroll
    for (int r = 0; r < 4; ++r) {
        float vvv = acc[r] + bof;
        int vn = pvs[q * 4 + r];
        out_pre[(size_t)vn * 64 + fbase + m] = vvv;
        p1 += vvv; p2 += vvv * vvv;
    }
    p1 += __shfl_xor(p1, 16); p2 += __shfl_xor(p2, 16);
    p1 += __shfl_xor(p1, 32); p2 += __shfl_xor(p2, 32);
    if (f < 16) {
        atomAddF(&bnsum[fbase + f], p1);
        atomAddF(&bnsum2[fbase + f], p2);
    }
}

// ---------------- BN (finalize folded in) + ReLU + global_add_pool ----------------
__global__ __launch_bounds__(256) void bn_pool(const float* __restrict__ out_pre, const int* __restrict__ batch,
                                               const float* __restrict__ bnsum, const float* __restrict__ bnsum2,
                                               const float* __restrict__ gamma, const float* __restrict__ beta,
                                               float* __restrict__ pooled) {
    __shared__ float red[256];
    int tid = threadIdx.x, f = tid & 63, q = tid >> 6;
    int base = blockIdx.x * 64;
    float mu = bnsum[f] * (1.0f / NN);
    float var = bnsum2[f] * (1.0f / NN) - mu * mu;
    float sc = gamma[f] * rsqrtf(var + 1e-5f);
    float sh = beta[f] - mu * sc;
    int b_first = batch[base < NN ? base : NN - 1];
    int last = base + 63; if (last >= NN) last = NN - 1;
    int b_last = batch[last];
    if (b_first == b_last) {
        float local = 0.f;
        for (int g = 0; g < 16; ++g) {
            int v = base + g * 4 + q;
            if (v < NN) local += fmaxf(out_pre[(size_t)v * 64 + f] * sc + sh, 0.f);
        }
        red[tid] = local;
        __syncthreads();
        if (tid < 64) atomAddF(&pooled[b_first * 64 + f], red[f] + red[f + 64] + red[f + 128] + red[f + 192]);
    } else {
        for (int g = 0; g < 16; ++g) {
            int v = base + g * 4 + q;
            if (v < NN) {
                float val = fmaxf(out_pre[(size_t)v * 64 + f] * sc + sh, 0.f);
                atomAddF(&pooled[batch[v] * 64 + f], val);
            }
        }
    }
}

// ---------------- head MLP: relu(pooled@Wm1+bm1)@Wm2+bm2 ----------------
__global__ void head_kernel(const float* __restrict__ pooled,
                            const float* __restrict__ Wm1, const float* __restrict__ bm1,
                            const float* __restrict__ Wm2, const float* __restrict__ bm2,
                            float* __restrict__ out) {
    __shared__ float ts[64][104];
    int tid = threadIdx.x;
    for (int t = tid; t < 64 * 100; t += 256) {
        int b = t / 100, j = t % 100;
        float acc = bm1[j];
        for (int k = 0; k < 64; k++) acc += pooled[b * 64 + k] * Wm1[k * 100 + j];
        ts[b][j] = fmaxf(acc, 0.f);
    }
    __syncthreads();
    if (tid < 64) {
        float acc = bm2[0];
        for (int j = 0; j < 100; j++) acc += ts[tid][j] * Wm2[j];
        out[tid] = acc;
    }
}

extern "C" void kernel_launch(void* const* d_in, const int* in_sizes, int n_in,
                              void* d_out, int out_size, void* d_ws, size_t ws_size,
                              hipStream_t stream) {
    const float* x    = (const float*)d_in[0];
    const float* ea   = (const float*)d_in[1];
    const int*   ei   = (const int*)d_in[2];
    const int*   batch= (const int*)d_in[3];
    const float* W1   = (const float*)d_in[4];
    const float* b1   = (const float*)d_in[5];
    const float* W2   = (const float*)d_in[6];
    const float* b2   = (const float*)d_in[7];
    const float* We   = (const float*)d_in[8];
    const float* be   = (const float*)d_in[9];
    const float* Wp   = (const float*)d_in[10];
    const float* bp   = (const float*)d_in[11];
    const float* Wo   = (const float*)d_in[12];
    const float* bo   = (const float*)d_in[13];
    const float* Wl   = (const float*)d_in[14];
    const float* bl   = (const float*)d_in[15];
    const float* gamma= (const float*)d_in[16];
    const float* beta = (const float*)d_in[17];
    const float* Wm1  = (const float*)d_in[18];
    const float* bm1  = (const float*)d_in[19];
    const float* Wm2  = (const float*)d_in[20];
    const float* bm2  = (const float*)d_in[21];

    float* ws = (float*)d_ws;
    constexpr size_t NF = (size_t)NN * 64;              // 6,400,000
    const size_t o_x2     = 0;
    const size_t o_B      = NF;                         // Bnb bf16 (NF ushorts)
    const size_t o_A      = 2 * NF;
    const size_t o_outpre = 3 * NF;
    const size_t o_start  = 4 * NF;                     // NN+1 uints -> reserve 100016
    const size_t o_cnt_i  = o_start + 100016;           // NN uints (memset 0)
    const size_t o_bsum   = o_cnt_i + 100000;           // 512
    const size_t o_boff   = o_bsum + 512;               // 512
    const size_t o_perm   = o_boff + 512;               // NN ints
    const size_t o_eab    = o_perm + 100000;            // (NE+1)*16 bf16 -> 12,800,016
    const size_t o_srcs   = o_eab + 12800016;           // NE+1 ints -> 1,600,016
    const size_t o_Wtb    = o_srcs + 1600016;           // 64*832 bf16 = 26,624 floats
    const size_t o_Wepp   = o_Wtb + 26624;              // 512 uints
    const size_t o_bpF    = o_Wepp + 512;
    const size_t o_boF    = o_bpF + 64;
    const size_t o_bnscale= o_boF + 64;
    const size_t o_bnshift= o_bnscale + 64;
    const size_t o_pooled = o_bnshift + 64;             // zero block: pooled + bnsum + bnsum2
    const size_t o_bnsum  = o_pooled + 64 * 64;
    const size_t o_bnsum2 = o_bnsum + 64;

    // Aliased scratch:
    //  bh    [256][391] -> cnt_i+bsum+boff region (dead after scatter_kernel)
    //  bhoff [256][391] -> front of out_pre (dead until agg_post)
    //  rank_g [NN]      -> out_pre + 100,096
    unsigned* bh     = (unsigned*)(ws + o_cnt_i);
    unsigned* bhoff  = (unsigned*)(ws + o_outpre);
    unsigned* rank_g = (unsigned*)(ws + o_outpre + 100096);

    hipMemsetAsync(ws + o_cnt_i, 0, 100000 * sizeof(unsigned), stream);
    hipMemsetAsync(ws + o_pooled, 0, (64 * 64 + 128) * sizeof(float), stream);

    fold_weights<<<213, 256, 0, stream>>>(Wo, Wl, bo, bl, We, Wp, bp, be,
                                          (__hip_bfloat16*)(ws + o_Wtb), (unsigned*)(ws + o_Wepp),
                                          ws + o_bpF, ws + o_boF);
    node_pre<<<768, 256, 0, stream>>>(x, W1, b1, W2, b2, Wp,
                                      ws + o_x2, ws + o_A, (__hip_bfloat16*)(ws + o_B));
    hist_kernel<<<6250, 256, 0, stream>>>(ei, (unsigned*)(ws + o_cnt_i));
    scan_blocksum<<<NSCAN_BLOCKS, 256, 0, stream>>>((unsigned*)(ws + o_cnt_i), (unsigned*)(ws + o_bsum));
    scan_top<<<1, 512, 0, stream>>>((unsigned*)(ws + o_bsum), (unsigned*)(ws + o_boff),
                                    (unsigned*)(ws + o_start));
    scan_final<<<NSCAN_BLOCKS, 256, 0, stream>>>((unsigned*)(ws + o_cnt_i), (unsigned*)(ws + o_boff),
                                                 (unsigned*)(ws + o_start));
    scatter_kernel<<<6250, 256, 0, stream>>>(ei, ea, (const unsigned*)(ws + o_start),
                                             (unsigned*)(ws + o_cnt_i),
                                             (__hip_bfloat16*)(ws + o_eab), (int*)(ws + o_srcs));
    deg_localhist<<<NSCAN_BLOCKS, 256, 0, stream>>>((const unsigned*)(ws + o_start), bh, rank_g);
    deg_colscan<<<1, 256, 0, stream>>>(bh, bhoff);
    deg_place<<<NSCAN_BLOCKS, 256, 0, stream>>>((const unsigned*)(ws + o_start), bhoff, rank_g,
                                                (int*)(ws + o_perm));
    agg_post_kernel<<<6250, 256, 0, stream>>>((const __hip_bfloat16*)(ws + o_eab),
                                              (const int*)(ws + o_srcs),
                                              (const unsigned*)(ws + o_start),
                                              (const int*)(ws + o_perm),
                                              ws + o_A, (const unsigned short*)(ws + o_B), ws + o_x2,
                                              (const unsigned*)(ws + o_Wepp), ws + o_bpF,
                                              (const __hip_bfloat16*)(ws + o_Wtb), ws + o_boF,
                                              ws + o_outpre, ws + o_bnsum, ws + o_bnsum2);
    bn_pool<<<1563, 256, 0, stream>>>(ws + o_outpre, batch,
                                      ws + o_bnsum, ws + o_bnsum2, gamma, beta, ws + o_pooled);
    head_kernel<<<1, 256, 0, stream>>>(ws + o_pooled, Wm1, bm1, Wm2, bm2, (float*)d_out);
}

// Round 7
// 688.473 us; speedup vs baseline: 1.7456x; 1.0658x over previous
//
#include <hip/hip_runtime.h>
#include <hip/hip_bf16.h>
#include <math.h>

#define NN 100000
#define NE 1600000
#define FF 64
#define NB 64
#define NSCAN_BLOCKS 391   // ceil(NN/256)

// avg_deg['log'] = sum(log(i+1)*DEG[i]) / sum(DEG)
__device__ __constant__ float AVG_LOG_F = 1.9595436f;

typedef short short8 __attribute__((ext_vector_type(8)));
typedef float f32x4 __attribute__((ext_vector_type(4)));

__device__ __forceinline__ void atomAddF(float* p, float v) {
    __hip_atomic_fetch_add(p, v, __ATOMIC_RELAXED, __HIP_MEMORY_SCOPE_AGENT);
}
__device__ __forceinline__ float bf2f(short v) {
    return __uint_as_float(((unsigned)(unsigned short)v) << 16);
}
__device__ __forceinline__ unsigned packbf2(float a, float b) {
    unsigned ua = (unsigned)(unsigned short)__bfloat16_as_short(__float2bfloat16(a));
    unsigned ub = (unsigned)(unsigned short)__bfloat16_as_short(__float2bfloat16(b));
    return ua | (ub << 16);
}
// legal may-alias dword load of two adjacent u16 LDS elements
__device__ __forceinline__ unsigned lds_pair(const unsigned short* p) {
    unsigned u;
    __builtin_memcpy(&u, p, 4);
    return u;
}
// D = a.lo*b.lo + a.hi*b.hi + c  (bf16 pairs, f32 accumulate)
__device__ __forceinline__ float dot2bf(unsigned a, unsigned b, float c) {
    float d;
    asm("v_dot2_f32_bf16 %0, %1, %2, %3" : "=v"(d) : "v"(a), "v"(b), "v"(c));
    return d;
}

// ---------------- fold weights: Wtb = (Wo@Wl)^T bf16; Wepp = packed-bf16 (We@Wp2); biases ----------------
__global__ void fold_weights(const float* __restrict__ Wo, const float* __restrict__ Wl,
                             const float* __restrict__ bo, const float* __restrict__ bl,
                             const float* __restrict__ We, const float* __restrict__ Wp,
                             const float* __restrict__ bp, const float* __restrict__ be,
                             __hip_bfloat16* __restrict__ Wtb,   // [64][832]  Wtb[f][k] = (Wo@Wl)[k][f]
                             unsigned* __restrict__ Wepp,        // [8][64] packed bf16 pairs of Wep[k][f]
                             float* __restrict__ bpF, float* __restrict__ boF) {
    int t = blockIdx.x * blockDim.x + threadIdx.x;
    if (t < 832 * 64) {
        int k = t >> 6, f = t & 63;
        float acc = 0.f;
        for (int j = 0; j < 64; j++) acc += Wo[k * 64 + j] * Wl[j * 64 + f];
        Wtb[f * 832 + k] = __float2bfloat16(acc);
    } else if (t < 832 * 64 + 512) {
        int u = t - 832 * 64; int k2 = u >> 6, f = u & 63;
        float a0 = 0.f, a1 = 0.f;
        for (int j = 0; j < 64; j++) {
            float wp = Wp[(128 + j) * 64 + f];
            a0 += We[(2 * k2) * 64 + j] * wp;
            a1 += We[(2 * k2 + 1) * 64 + j] * wp;
        }
        Wepp[k2 * 64 + f] = packbf2(a0, a1);
    } else if (t < 832 * 64 + 512 + 64) {
        int f = t - (832 * 64 + 512);
        float acc = bl[f];
        for (int j = 0; j < 64; j++) acc += bo[j] * Wl[j * 64 + f];
        boF[f] = acc;
    } else if (t < 832 * 64 + 512 + 128) {
        int f = t - (832 * 64 + 512 + 64);
        float acc = bp[f];
        for (int j = 0; j < 64; j++) acc += be[j] * Wp[(128 + j) * 64 + f];
        bpF[f] = acc;
    }
}

// ---------------- node pre-MLP + A/B projections + fused edge histogram ----------------
// weights in REGISTERS (packed bf16), dot2 math, LDS tiny broadcast buffer.
// The edge histogram runs as fire-and-forget no-return atomics overlapping node compute.
__global__ __launch_bounds__(256) void node_pre(const float* __restrict__ x,
                                                const float* __restrict__ W1, const float* __restrict__ b1,
                                                const float* __restrict__ W2, const float* __restrict__ b2,
                                                const float* __restrict__ Wp,
                                                const int* __restrict__ ei, unsigned* __restrict__ cnt_i,
                                                float* __restrict__ x2, float* __restrict__ A,
                                                __hip_bfloat16* __restrict__ Bnb) {
    __shared__ unsigned short xs[4][64], ts[4][32], x2s[4][64];
    int tid = threadIdx.x;
    int w = tid >> 6, f = tid & 63;
    int fm = f & 31;

    // fused histogram: grid-stride over edges; atomics are no-return -> non-blocking
    int nthreads = gridDim.x * 256;
    for (int e = blockIdx.x * 256 + tid; e < NE; e += nthreads)
        atomicAdd(&cnt_i[ei[NE + e]], 1u);

    // hoist all weights into registers as packed bf16 pairs (loop-invariant across nodes)
    unsigned w1p[32], w2p[16], wp0p[32], wp1p[32];
    #pragma unroll
    for (int k2 = 0; k2 < 32; ++k2)
        w1p[k2] = packbf2(W1[(2 * k2) * 32 + fm], W1[(2 * k2 + 1) * 32 + fm]);
    #pragma unroll
    for (int k2 = 0; k2 < 16; ++k2)
        w2p[k2] = packbf2(W2[(2 * k2) * 64 + f], W2[(2 * k2 + 1) * 64 + f]);
    #pragma unroll
    for (int k2 = 0; k2 < 32; ++k2) {
        wp0p[k2] = packbf2(Wp[(2 * k2) * 64 + f], Wp[(2 * k2 + 1) * 64 + f]);
        wp1p[k2] = packbf2(Wp[4096 + (2 * k2) * 64 + f], Wp[4096 + (2 * k2 + 1) * 64 + f]);
    }
    float b1f = b1[fm], b2f = b2[f];

    int wid = blockIdx.x * 4 + w;
    int nw = gridDim.x * 4;
    for (int v = wid; v < NN; v += nw) {
        float xv = x[(size_t)v * 64 + f];
        xs[w][f] = (unsigned short)__bfloat16_as_short(__float2bfloat16(xv));
        float t = b1f;
        #pragma unroll
        for (int k2 = 0; k2 < 32; ++k2) t = dot2bf(lds_pair(&xs[w][2 * k2]), w1p[k2], t);
        t = fmaxf(t, 0.f);
        if (f < 32) ts[w][f] = (unsigned short)__bfloat16_as_short(__float2bfloat16(t));
        float acc2 = b2f;
        #pragma unroll
        for (int k2 = 0; k2 < 16; ++k2) acc2 = dot2bf(lds_pair(&ts[w][2 * k2]), w2p[k2], acc2);
        x2[(size_t)v * 64 + f] = acc2;
        x2s[w][f] = (unsigned short)__bfloat16_as_short(__float2bfloat16(acc2));
        float aa = 0.f, bb = 0.f;
        #pragma unroll
        for (int k2 = 0; k2 < 32; ++k2) {
            unsigned xq = lds_pair(&x2s[w][2 * k2]);
            aa = dot2bf(xq, wp0p[k2], aa);
            bb = dot2bf(xq, wp1p[k2], bb);
        }
        A[(size_t)v * 64 + f] = aa;
        Bnb[(size_t)v * 64 + f] = __float2bfloat16(bb);
    }
}

// ---------------- counting sort of edges by dst: scans ----------------
__global__ void scan_blocksum(const unsigned* __restrict__ cnt_i, unsigned* __restrict__ bsum) {
    __shared__ unsigned red[256];
    int t = blockIdx.x * 256 + threadIdx.x;
    unsigned c = (t < NN) ? cnt_i[t] : 0u;
    red[threadIdx.x] = c; __syncthreads();
    for (int s = 128; s > 0; s >>= 1) {
        if (threadIdx.x < s) red[threadIdx.x] += red[threadIdx.x + s];
        __syncthreads();
    }
    if (threadIdx.x == 0) bsum[blockIdx.x] = red[0];
}

__global__ void scan_top(const unsigned* __restrict__ bsum, unsigned* __restrict__ boff,
                         unsigned* __restrict__ start) {
    __shared__ unsigned sh[512];
    int t = threadIdx.x;
    unsigned v = (t < NSCAN_BLOCKS) ? bsum[t] : 0u;
    sh[t] = v; __syncthreads();
    for (int d = 1; d < 512; d <<= 1) {
        unsigned add = (t >= d) ? sh[t - d] : 0u;
        __syncthreads();
        sh[t] += add;
        __syncthreads();
    }
    if (t < NSCAN_BLOCKS) boff[t] = sh[t] - v;   // exclusive
    if (t == 0) start[NN] = NE;
}

// scan_final fused with deg_localhist: degree key = cnt_i[v] (already loaded here)
__global__ __launch_bounds__(256) void scan_final_deg(const unsigned* __restrict__ cnt_i,
                                                      const unsigned* __restrict__ boff,
                                                      unsigned* __restrict__ start,
                                                      unsigned* __restrict__ bh,      // [256][NSCAN_BLOCKS]
                                                      unsigned* __restrict__ rank_g) {
    __shared__ unsigned sh[256];
    __shared__ unsigned short keys[256];
    int b = blockIdx.x, t = threadIdx.x;
    int v = b * 256 + t;
    unsigned c = (v < NN) ? cnt_i[v] : 0u;
    sh[t] = c;
    unsigned d = 0xFFFFu;                       // sentinel: matches no bin
    if (v < NN) d = (c > 255u) ? 255u : c;
    keys[t] = (unsigned short)d;
    __syncthreads();
    for (int dd = 1; dd < 256; dd <<= 1) {
        unsigned add = (t >= dd) ? sh[t - dd] : 0u;
        __syncthreads();
        sh[t] += add;
        __syncthreads();
    }
    if (v < NN) start[v] = boff[b] + sh[t] - c;  // exclusive scan
    // block-local degree histogram + stable ranks (keys visible via scan's barriers)
    unsigned cnt = 0;
    #pragma unroll 8
    for (int i = 0; i < 256; ++i) cnt += (keys[i] == (unsigned short)t) ? 1u : 0u;
    bh[t * NSCAN_BLOCKS + b] = cnt;
    if (v < NN) {
        unsigned r = 0;
        for (int i = 0; i < t; ++i) r += (keys[i] == (unsigned short)d) ? 1u : 0u;
        rank_g[v] = r;
    }
}

__global__ __launch_bounds__(256) void deg_colscan(const unsigned* __restrict__ bh,
                                                   unsigned* __restrict__ bhoff) {
    __shared__ unsigned sh[256];
    int bin = threadIdx.x;
    unsigned s = 0;
    for (int b = 0; b < NSCAN_BLOCKS; ++b) s += bh[bin * NSCAN_BLOCKS + b];
    sh[bin] = s;
    __syncthreads();
    for (int d = 1; d < 256; d <<= 1) {
        unsigned add = (bin >= d) ? sh[bin - d] : 0u;
        __syncthreads();
        sh[bin] += add;
        __syncthreads();
    }
    unsigned run = sh[bin] - s;   // exclusive bin offset
    for (int b = 0; b < NSCAN_BLOCKS; ++b) {
        unsigned c = bh[bin * NSCAN_BLOCKS + b];
        bhoff[bin * NSCAN_BLOCKS + b] = run;
        run += c;
    }
}

__global__ __launch_bounds__(256) void deg_place(const unsigned* __restrict__ cnt_i,
                                                 const unsigned* __restrict__ bhoff,
                                                 const unsigned* __restrict__ rank_g,
                                                 int* __restrict__ perm) {
    int t0 = threadIdx.x, b = blockIdx.x;
    int t = b * 256 + t0;
    if (t < NN) {
        unsigned d = cnt_i[t];
        if (d > 255u) d = 255u;
        perm[bhoff[d * NSCAN_BLOCKS + b] + rank_g[t]] = t;
    }
}

// scatter: materialize sorted edge payloads (src and bf16 edge_attr); pads element NE
__global__ void scatter_kernel(const int* __restrict__ ei, const float* __restrict__ ea,
                               const unsigned* __restrict__ start,
                               unsigned* __restrict__ cnt_i,
                               __hip_bfloat16* __restrict__ eab, int* __restrict__ src_s) {
    int t = blockIdx.x * blockDim.x + threadIdx.x;
    if (t == 0) {
        src_s[NE] = 0;
        short8 z = {0, 0, 0, 0, 0, 0, 0, 0};
        short8* p = (short8*)(eab + (size_t)NE * 16);
        p[0] = z; p[1] = z;
    }
    if (t < NE) {
        int d = ei[NE + t];
        unsigned old = atomicSub(&cnt_i[d], 1u);
        unsigned pos = start[d] + old - 1u;
        src_s[pos] = ei[t];
        const float4* s4 = (const float4*)(ea + (size_t)t * 16);
        float4 a = s4[0], b = s4[1], c = s4[2], e = s4[3];
        short8 o0, o1;
        o0[0] = (short)__bfloat16_as_short(__float2bfloat16(a.x));
        o0[1] = (short)__bfloat16_as_short(__float2bfloat16(a.y));
        o0[2] = (short)__bfloat16_as_short(__float2bfloat16(a.z));
        o0[3] = (short)__bfloat16_as_short(__float2bfloat16(a.w));
        o0[4] = (short)__bfloat16_as_short(__float2bfloat16(b.x));
        o0[5] = (short)__bfloat16_as_short(__float2bfloat16(b.y));
        o0[6] = (short)__bfloat16_as_short(__float2bfloat16(b.z));
        o0[7] = (short)__bfloat16_as_short(__float2bfloat16(b.w));
        o1[0] = (short)__bfloat16_as_short(__float2bfloat16(c.x));
        o1[1] = (short)__bfloat16_as_short(__float2bfloat16(c.y));
        o1[2] = (short)__bfloat16_as_short(__float2bfloat16(c.z));
        o1[3] = (short)__bfloat16_as_short(__float2bfloat16(c.w));
        o1[4] = (short)__bfloat16_as_short(__float2bfloat16(e.x));
        o1[5] = (short)__bfloat16_as_short(__float2bfloat16(e.y));
        o1[6] = (short)__bfloat16_as_short(__float2bfloat16(e.z));
        o1[7] = (short)__bfloat16_as_short(__float2bfloat16(e.w));
        short8* dst8 = (short8*)(eab + (size_t)pos * 16);
        dst8[0] = o0; dst8[1] = o1;
    }
}

// ---------------- fused aggregation + post GEMM (MFMA) + BN stats ----------------
// Software-pipelined gather chain: src prefetched 4-5 slots ahead, Bnb-row (bn) 2-3 slots
// ahead, e-rows for both unrolled slots issued at body top. All prefetch indices are
// clamp-safe; clamped duplicates are idempotent for min/max and zeroed for sums.
__global__ __launch_bounds__(256) void agg_post_kernel(const __hip_bfloat16* __restrict__ eab,
                                                       const int* __restrict__ src_s,
                                                       const unsigned* __restrict__ start,
                                                       const int* __restrict__ perm,
                                                       const float* __restrict__ A,
                                                       const unsigned short* __restrict__ Bnb,
                                                       const float* __restrict__ x2,
                                                       const unsigned* __restrict__ Wepp, const float* __restrict__ bpF,
                                                       const __hip_bfloat16* __restrict__ Wtb,
                                                       const float* __restrict__ boF,
                                                       float* __restrict__ out_pre,
                                                       float* __restrict__ bnsum, float* __restrict__ bnsum2) {
    __shared__ __hip_bfloat16 As[16 * 840];
    __shared__ int pvs[16];
    int tid = threadIdx.x;
    int w = __builtin_amdgcn_readfirstlane(tid >> 6);   // wave id, force SGPR
    int f = tid & 63;
    int base = blockIdx.x * 16;      // 6250 blocks exactly

    unsigned wcolp[8];
    #pragma unroll
    for (int k = 0; k < 8; k++) wcolp[k] = Wepp[k * 64 + f];
    float bpf = bpF[f];

    int vv[4]; unsigned s0[4]; int len[4], lim[4]; float av[4];
    float sA[4] = {0.f, 0.f, 0.f, 0.f}, s2A[4] = {0.f, 0.f, 0.f, 0.f};
    float mnA[4], mxA[4];
    int maxlen = 0;
    #pragma unroll
    for (int g = 0; g < 4; ++g) {
        int v = __builtin_amdgcn_readfirstlane(perm[base + g * 4 + w]);
        vv[g] = v;
        if (f == 0) pvs[g * 4 + w] = v;
        unsigned a = start[v], b = start[v + 1];
        s0[g] = a; len[g] = (int)(b - a);
        lim[g] = len[g] > 0 ? len[g] - 1 : 0;
        maxlen = max(maxlen, len[g]);
        av[g] = A[(size_t)v * 64 + f] + bpf;
        mnA[g] = INFINITY; mxA[g] = -INFINITY;
    }

    // pipeline prologue: bn for slots 0,1; src for slots 2,3
    int sP0[4], sP1[4];
    float bnC0[4], bnC1[4];
    #pragma unroll
    for (int g = 0; g < 4; ++g) {
        int a0 = src_s[s0[g]];                                       // slot 0 (min(0,lim)=0)
        int a1 = src_s[s0[g] + (unsigned)min(1, lim[g])];            // slot 1
        bnC0[g] = bf2f((short)Bnb[((size_t)a0 << 6) + f]);
        bnC1[g] = bf2f((short)Bnb[((size_t)a1 << 6) + f]);
        sP0[g] = src_s[s0[g] + (unsigned)min(2, lim[g])];            // slot 2
        sP1[g] = src_s[s0[g] + (unsigned)min(3, lim[g])];            // slot 3
    }

    for (int j = 0; j < maxlen; j += 2) {
        int sN0[4], sN1[4];
        float bnN0[4], bnN1[4];
        unsigned e0[4][8], e1[4][8];
        #pragma unroll
        for (int g = 0; g < 4; ++g) {
            sN0[g] = src_s[s0[g] + (unsigned)min(j + 4, lim[g])];    // src 4 ahead
            sN1[g] = src_s[s0[g] + (unsigned)min(j + 5, lim[g])];    // src 5 ahead
            bnN0[g] = bf2f((short)Bnb[((size_t)sP0[g] << 6) + f]);   // bn for slot j+2
            bnN1[g] = bf2f((short)Bnb[((size_t)sP1[g] << 6) + f]);   // bn for slot j+3
            const unsigned* p0 = (const unsigned*)(eab + (size_t)(s0[g] + (unsigned)min(j, lim[g])) * 16);
            const unsigned* p1 = (const unsigned*)(eab + (size_t)(s0[g] + (unsigned)min(j + 1, lim[g])) * 16);
            #pragma unroll
            for (int k = 0; k < 8; ++k) { e0[g][k] = p0[k]; e1[g][k] = p1[k]; }
        }
        #pragma unroll
        for (int g = 0; g < 4; ++g) {
            float h = av[g] + bnC0[g];
            #pragma unroll
            for (int k = 0; k < 8; k++) h = dot2bf(e0[g][k], wcolp[k], h);
            bool valid = j < len[g];
            float hm = valid ? h : 0.f;
            sA[g] += hm; s2A[g] += hm * hm;
            mnA[g] = fminf(mnA[g], h);
            mxA[g] = fmaxf(mxA[g], h);
        }
        #pragma unroll
        for (int g = 0; g < 4; ++g) {
            float h = av[g] + bnC1[g];
            #pragma unroll
            for (int k = 0; k < 8; k++) h = dot2bf(e1[g][k], wcolp[k], h);
            bool valid = (j + 1) < len[g];
            float hm = valid ? h : 0.f;
            sA[g] += hm; s2A[g] += hm * hm;
            mnA[g] = fminf(mnA[g], h);
            mxA[g] = fmaxf(mxA[g], h);
        }
        #pragma unroll
        for (int g = 0; g < 4; ++g) {
            bnC0[g] = bnN0[g]; bnC1[g] = bnN1[g];
            sP0[g] = sN0[g];   sP1[g] = sN1[g];
        }
    }

    #pragma unroll
    for (int g = 0; g < 4; ++g) {
        int n = g * 4 + w;
        int v = vv[g];
        float c = (float)len[g];
        float d = fmaxf(c, 1.f);
        float inv = 1.f / d;
        float mean = sA[g] * inv, mean2 = s2A[g] * inv;
        float sd = sqrtf(fmaxf(mean2 - mean * mean, 0.f) + 1e-5f);
        bool has = len[g] > 0;
        float mn = has ? mnA[g] : 0.f;
        float mx = has ? mxA[g] : 0.f;
        float l = __logf(d + 1.f);
        float amp = l * (1.0f / 1.9595436f);
        float iamp = 1.9595436f / l;
        __hip_bfloat16* row = &As[n * 840];
        row[f]        = __float2bfloat16(x2[(size_t)v * 64 + f]);
        row[64 + f]   = __float2bfloat16(mean);
        row[128 + f]  = __float2bfloat16(mn);
        row[192 + f]  = __float2bfloat16(mx);
        row[256 + f]  = __float2bfloat16(sd);
        row[320 + f]  = __float2bfloat16(mean * amp);
        row[384 + f]  = __float2bfloat16(mn * amp);
        row[448 + f]  = __float2bfloat16(mx * amp);
        row[512 + f]  = __float2bfloat16(sd * amp);
        row[576 + f]  = __float2bfloat16(mean * iamp);
        row[640 + f]  = __float2bfloat16(mn * iamp);
        row[704 + f]  = __float2bfloat16(mx * iamp);
        row[768 + f]  = __float2bfloat16(sd * iamp);
    }
    __syncthreads();

    // MFMA phase: lane = m + 16q; A[m][k=q*8+j], B[k][n=m]; D: col=lane&15, row=q*4+reg
    int m = f & 15, q = f >> 4;
    int fbase = w * 16;
    f32x4 acc = {0.f, 0.f, 0.f, 0.f};
    const __hip_bfloat16* arow = &As[m * 840 + q * 8];
    const __hip_bfloat16* brow = &Wtb[(size_t)(fbase + m) * 832 + q * 8];
    #pragma unroll
    for (int s = 0; s < 26; ++s) {
        short8 af = *(const short8*)(arow + s * 32);
        short8 bf = *(const short8*)(brow + s * 32);
        acc = __builtin_amdgcn_mfma_f32_16x16x32_bf16(af, bf, acc, 0, 0, 0);
    }

    float bof = boF[fbase + m];
    float p1 = 0.f, p2 = 0.f;
    #pragma unroll
    for (int r = 0; r < 4; ++r) {
        float vvv = acc[r] + bof;
        int vn = pvs[q * 4 + r];
        out_pre[(size_t)vn * 64 + fbase + m] = vvv;
        p1 += vvv; p2 += vvv * vvv;
    }
    p1 += __shfl_xor(p1, 16); p2 += __shfl_xor(p2, 16);
    p1 += __shfl_xor(p1, 32); p2 += __shfl_xor(p2, 32);
    if (f < 16) {
        atomAddF(&bnsum[fbase + f], p1);
        atomAddF(&bnsum2[fbase + f], p2);
    }
}

// ---------------- BN (finalize folded in) + ReLU + global_add_pool ----------------
__global__ __launch_bounds__(256) void bn_pool(const float* __restrict__ out_pre, const int* __restrict__ batch,
                                               const float* __restrict__ bnsum, const float* __restrict__ bnsum2,
                                               const float* __restrict__ gamma, const float* __restrict__ beta,
                                               float* __restrict__ pooled) {
    __shared__ float red[256];
    int tid = threadIdx.x, f = tid & 63, q = tid >> 6;
    int base = blockIdx.x * 64;
    float mu = bnsum[f] * (1.0f / NN);
    float var = bnsum2[f] * (1.0f / NN) - mu * mu;
    float sc = gamma[f] * rsqrtf(var + 1e-5f);
    float sh = beta[f] - mu * sc;
    int b_first = batch[base < NN ? base : NN - 1];
    int last = base + 63; if (last >= NN) last = NN - 1;
    int b_last = batch[last];
    if (b_first == b_last) {
        float local = 0.f;
        for (int g = 0; g < 16; ++g) {
            int v = base + g * 4 + q;
            if (v < NN) local += fmaxf(out_pre[(size_t)v * 64 + f] * sc + sh, 0.f);
        }
        red[tid] = local;
        __syncthreads();
        if (tid < 64) atomAddF(&pooled[b_first * 64 + f], red[f] + red[f + 64] + red[f + 128] + red[f + 192]);
    } else {
        for (int g = 0; g < 16; ++g) {
            int v = base + g * 4 + q;
            if (v < NN) {
                float val = fmaxf(out_pre[(size_t)v * 64 + f] * sc + sh, 0.f);
                atomAddF(&pooled[batch[v] * 64 + f], val);
            }
        }
    }
}

// ---------------- head MLP: relu(pooled@Wm1+bm1)@Wm2+bm2 ----------------
__global__ void head_kernel(const float* __restrict__ pooled,
                            const float* __restrict__ Wm1, const float* __restrict__ bm1,
                            const float* __restrict__ Wm2, const float* __restrict__ bm2,
                            float* __restrict__ out) {
    __shared__ float ts[64][104];
    int tid = threadIdx.x;
    for (int t = tid; t < 64 * 100; t += 256) {
        int b = t / 100, j = t % 100;
        float acc = bm1[j];
        for (int k = 0; k < 64; k++) acc += pooled[b * 64 + k] * Wm1[k * 100 + j];
        ts[b][j] = fmaxf(acc, 0.f);
    }
    __syncthreads();
    if (tid < 64) {
        float acc = bm2[0];
        for (int j = 0; j < 100; j++) acc += ts[tid][j] * Wm2[j];
        out[tid] = acc;
    }
}

extern "C" void kernel_launch(void* const* d_in, const int* in_sizes, int n_in,
                              void* d_out, int out_size, void* d_ws, size_t ws_size,
                              hipStream_t stream) {
    const float* x    = (const float*)d_in[0];
    const float* ea   = (const float*)d_in[1];
    const int*   ei   = (const int*)d_in[2];
    const int*   batch= (const int*)d_in[3];
    const float* W1   = (const float*)d_in[4];
    const float* b1   = (const float*)d_in[5];
    const float* W2   = (const float*)d_in[6];
    const float* b2   = (const float*)d_in[7];
    const float* We   = (const float*)d_in[8];
    const float* be   = (const float*)d_in[9];
    const float* Wp   = (const float*)d_in[10];
    const float* bp   = (const float*)d_in[11];
    const float* Wo   = (const float*)d_in[12];
    const float* bo   = (const float*)d_in[13];
    const float* Wl   = (const float*)d_in[14];
    const float* bl   = (const float*)d_in[15];
    const float* gamma= (const float*)d_in[16];
    const float* beta = (const float*)d_in[17];
    const float* Wm1  = (const float*)d_in[18];
    const float* bm1  = (const float*)d_in[19];
    const float* Wm2  = (const float*)d_in[20];
    const float* bm2  = (const float*)d_in[21];

    float* ws = (float*)d_ws;
    constexpr size_t NF = (size_t)NN * 64;              // 6,400,000
    const size_t o_x2     = 0;
    const size_t o_B      = NF;                         // Bnb bf16 (NF ushorts)
    const size_t o_A      = 2 * NF;
    const size_t o_outpre = 3 * NF;
    const size_t o_start  = 4 * NF;                     // NN+1 uints -> reserve 100016
    const size_t o_cnt_i  = o_start + 100016;           // NN uints (memset 0)
    const size_t o_bsum   = o_cnt_i + 100000;           // 512
    const size_t o_boff   = o_bsum + 512;               // 512
    const size_t o_perm   = o_boff + 512;               // NN ints
    const size_t o_eab    = o_perm + 100000;            // (NE+1)*16 bf16 -> 12,800,016
    const size_t o_srcs   = o_eab + 12800016;           // NE+1 ints -> 1,600,016
    const size_t o_Wtb    = o_srcs + 1600016;           // 64*832 bf16 = 26,624 floats
    const size_t o_Wepp   = o_Wtb + 26624;              // 512 uints
    const size_t o_bpF    = o_Wepp + 512;
    const size_t o_boF    = o_bpF + 64;
    const size_t o_pooled = o_boF + 64;                 // zero block: pooled + bnsum + bnsum2
    const size_t o_bnsum  = o_pooled + 64 * 64;
    const size_t o_bnsum2 = o_bnsum + 64;

    // Aliased deg-sort scratch in the out_pre region (dead until agg_post; cnt_i stays
    // live for scatter so nothing may alias it before then):
    //  bhoff  [256][391] at o_outpre
    //  rank_g [NN]       at o_outpre + 100,096
    //  bh     [256][391] at o_outpre + 200,096
    unsigned* bhoff  = (unsigned*)(ws + o_outpre);
    unsigned* rank_g = (unsigned*)(ws + o_outpre + 100096);
    unsigned* bh     = (unsigned*)(ws + o_outpre + 200096);

    hipMemsetAsync(ws + o_cnt_i, 0, 100000 * sizeof(unsigned), stream);
    hipMemsetAsync(ws + o_pooled, 0, (64 * 64 + 128) * sizeof(float), stream);

    fold_weights<<<213, 256, 0, stream>>>(Wo, Wl, bo, bl, We, Wp, bp, be,
                                          (__hip_bfloat16*)(ws + o_Wtb), (unsigned*)(ws + o_Wepp),
                                          ws + o_bpF, ws + o_boF);
    node_pre<<<768, 256, 0, stream>>>(x, W1, b1, W2, b2, Wp,
                                      ei, (unsigned*)(ws + o_cnt_i),
                                      ws + o_x2, ws + o_A, (__hip_bfloat16*)(ws + o_B));
    scan_blocksum<<<NSCAN_BLOCKS, 256, 0, stream>>>((unsigned*)(ws + o_cnt_i), (unsigned*)(ws + o_bsum));
    scan_top<<<1, 512, 0, stream>>>((unsigned*)(ws + o_bsum), (unsigned*)(ws + o_boff),
                                    (unsigned*)(ws + o_start));
    scan_final_deg<<<NSCAN_BLOCKS, 256, 0, stream>>>((unsigned*)(ws + o_cnt_i), (unsigned*)(ws + o_boff),
                                                     (unsigned*)(ws + o_start), bh, rank_g);
    deg_colscan<<<1, 256, 0, stream>>>(bh, bhoff);
    deg_place<<<NSCAN_BLOCKS, 256, 0, stream>>>((const unsigned*)(ws + o_cnt_i), bhoff, rank_g,
                                                (int*)(ws + o_perm));
    scatter_kernel<<<6250, 256, 0, stream>>>(ei, ea, (const unsigned*)(ws + o_start),
                                             (unsigned*)(ws + o_cnt_i),
                                             (__hip_bfloat16*)(ws + o_eab), (int*)(ws + o_srcs));
    agg_post_kernel<<<6250, 256, 0, stream>>>((const __hip_bfloat16*)(ws + o_eab),
                                              (const int*)(ws + o_srcs),
                                              (const unsigned*)(ws + o_start),
                                              (const int*)(ws + o_perm),
                                              ws + o_A, (const unsigned short*)(ws + o_B), ws + o_x2,
                                              (const unsigned*)(ws + o_Wepp), ws + o_bpF,
                                              (const __hip_bfloat16*)(ws + o_Wtb), ws + o_boF,
                                              ws + o_outpre, ws + o_bnsum, ws + o_bnsum2);
    bn_pool<<<1563, 256, 0, stream>>>(ws + o_outpre, batch,
                                      ws + o_bnsum, ws + o_bnsum2, gamma, beta, ws + o_pooled);
    head_kernel<<<1, 256, 0, stream>>>(ws + o_pooled, Wm1, bm1, Wm2, bm2, (float*)d_out);
}